// Round 5
// baseline (20889.534 us; speedup 1.0000x reference)
//
#include <hip/hip_runtime.h>
#include <math.h>

#define B 64
#define TIN 128
#define N_IN 256
#define M 1024
#define O_DIM 512
#define LM 2048
#define TDEC 64
#define M3 3072
#define ECH 16   // encoder gi timestep chunk
#define NBLK 256

typedef short bf16x8 __attribute__((ext_vector_type(8)));
typedef float floatx4 __attribute__((ext_vector_type(4)));

__device__ __forceinline__ unsigned short f2bf(float f) {
    unsigned int u = __float_as_uint(f);
    u += 0x7FFFu + ((u >> 16) & 1u);      // round-to-nearest-even
    return (unsigned short)(u >> 16);
}
__device__ __forceinline__ float sigm(float x) { return 1.f / (1.f + expf(-x)); }

// hand-rolled grid barrier: monotone counter, all NBLK blocks co-resident.
__device__ __forceinline__ void gsync(unsigned* bar, unsigned& phase) {
    __syncthreads();
    if (threadIdx.x == 0) {
        __threadfence();
        phase += 1;
        __hip_atomic_fetch_add(bar, 1u, __ATOMIC_RELEASE, __HIP_MEMORY_SCOPE_AGENT);
        const unsigned target = phase * NBLK;
        while (__hip_atomic_load(bar, __ATOMIC_ACQUIRE, __HIP_MEMORY_SCOPE_AGENT) < target)
            __builtin_amdgcn_s_sleep(2);
        __threadfence();
    }
    __syncthreads();
}

// ---------------------------------------------------------------------------
// pre-kernels: casts / transpose
// ---------------------------------------------------------------------------
__global__ __launch_bounds__(256) void cast_bf(const float* __restrict__ in,
                                               short* __restrict__ out, int n) {
    int i = blockIdx.x * 256 + threadIdx.x;
    if (i < n) out[i] = (short)f2bf(in[i]);
}

__global__ __launch_bounds__(256) void transpose_X_bf(const float* __restrict__ X,
                                                      short* __restrict__ Xt) {
    int idx = blockIdx.x * 256 + threadIdx.x;   // t*(B*N) + b*N + n
    int n = idx & (N_IN - 1);
    int b = (idx >> 8) & (B - 1);
    int t = idx >> 14;
    Xt[idx] = (short)f2bf(X[(b * TIN + t) * N_IN + n]);
}

// ---------------------------------------------------------------------------
// megakernel params
// ---------------------------------------------------------------------------
struct Params {
    const short *Xt;
    short *seqA;
    float *gi;                                   // ECH*B*M3 fp32 chunk buffer
    const short *we_ih0, *we_hh0, *we_ih1, *we_hh1;
    const short *wd_ih0, *wd_hh0, *wd_ih1, *wd_hh1, *wfc1, *wfc2;
    const float *enc_bih0, *enc_bhh0, *enc_bih1, *enc_bhh1;
    const float *dec_bih0, *dec_bhh0, *dec_bih1, *dec_bhh1;
    const float *fc1_b, *ln_g, *ln_b, *fc2_b;
    float *h0f, *h1f;
    short *h0b, *h1b;                            // 2x B*M ping-pong each
    const short *yb;                             // Y0 bf16
    float *zb;                                   // B*LM fp32
    short *zbb;                                  // B*LM bf16
    float *out;                                  // d_out logits
    unsigned *bar;                               // grid barrier counter
};

// ---------------------------------------------------------------------------
// One persistent kernel: full encoder + decoder. 256 blocks x 256 threads.
// ---------------------------------------------------------------------------
__global__ __launch_bounds__(256, 1) void mega(Params p) {
    const int blk  = blockIdx.x;
    const int tid  = threadIdx.x;
    const int wave = tid >> 6;
    const int lane = tid & 63;
    const int lrow = lane & 15;
    const int ko8  = (lane >> 4) * 8;
    const int wid  = blk * 4 + wave;            // 0..1023
    // epilogue / reduce thread mapping
    const int erow = tid >> 4, ecol = tid & 15;
    const int sl = (erow >> 2) * 16 + ecol, rg = erow & 3;
    unsigned ph = 0;

    __shared__ float l4[4][4][64][4];           // [gate][wave][lane][i]
    __shared__ short ylds[16][520];             // +8 pad: 2-way banks only
    __shared__ float redA[4], redB[4];

    // ================= encoder =================
    #pragma unroll 1
    for (int layer = 0; layer < 2; ++layer) {
        const short* Wih = layer ? p.we_ih1 : p.we_ih0;
        const short* Whh = layer ? p.we_hh1 : p.we_hh0;
        const float* bih = layer ? p.enc_bih1 : p.enc_bih0;
        const float* bhh = layer ? p.enc_bhh1 : p.enc_bhh0;
        const short* inseq = layer ? p.seqA : p.Xt;
        const int Kin = layer ? M : N_IN;
        float* hf = layer ? p.h1f : p.h0f;
        short* hb = layer ? p.h1b : p.h0b;
        #pragma unroll 1
        for (int c = 0; c < TIN / ECH; ++c) {
            // ---- gi GEMM for ECH steps: rows=ECH*B=1024, cols=3072 ----
            {
                const short* Abase = inseq + (size_t)c * ECH * B * Kin;
                #pragma unroll 1
                for (int T = wid; T < 64 * (M3 / 16); T += 1024) {
                    int rt = T & 63, ct = T >> 6;
                    int r0 = rt * 16, c0 = ct * 16;
                    const short* ap = Abase + (size_t)(r0 + lrow) * Kin + ko8;
                    const short* wp = Wih + (size_t)(c0 + lrow) * Kin + ko8;
                    floatx4 acc = {0.f, 0.f, 0.f, 0.f};
                    #pragma unroll 4
                    for (int k = 0; k < Kin; k += 32)
                        acc = __builtin_amdgcn_mfma_f32_16x16x32_bf16(
                            *(const bf16x8*)(ap + k), *(const bf16x8*)(wp + k),
                            acc, 0, 0, 0);
                    int col = c0 + lrow;
                    float bv = bih[col];
                    int rbase = r0 + (lane >> 4) * 4;
                    #pragma unroll
                    for (int i = 0; i < 4; ++i)
                        p.gi[(size_t)(rbase + i) * M3 + col] = acc[i] + bv;
                }
            }
            gsync(p.bar, ph);
            // ---- ECH sequential GRU steps, one 16x16 tile per block ----
            #pragma unroll 1
            for (int tt = 0; tt < ECH; ++tt) {
                int t = c * ECH + tt;
                int pin = t & 1, pout = pin ^ 1;
                const short* hin = hb + (size_t)pin * B * M;
                short* hout = hb + (size_t)pout * B * M;
                short* so = (layer == 0) ? (p.seqA + (size_t)t * B * M) : nullptr;
                const float* gi = p.gi + (size_t)tt * B * M3;
                int mt = blk & 63, bt = blk >> 6;
                int m0 = mt * 16, r0 = bt * 16;
                const int Kq = M >> 2;
                const short* ap = hin + (size_t)(r0 + lrow) * M + wave * Kq + ko8;
                const short* wr = Whh + (size_t)(m0 + lrow) * M + wave * Kq + ko8;
                const short* wz = wr + (size_t)M * M;
                const short* wn = wr + (size_t)2 * M * M;
                floatx4 ar = {0.f,0.f,0.f,0.f}, az = {0.f,0.f,0.f,0.f},
                        ah = {0.f,0.f,0.f,0.f};
                #pragma unroll
                for (int k = 0; k < Kq; k += 32) {
                    bf16x8 a = *(const bf16x8*)(ap + k);
                    ar = __builtin_amdgcn_mfma_f32_16x16x32_bf16(a, *(const bf16x8*)(wr + k), ar, 0, 0, 0);
                    az = __builtin_amdgcn_mfma_f32_16x16x32_bf16(a, *(const bf16x8*)(wz + k), az, 0, 0, 0);
                    ah = __builtin_amdgcn_mfma_f32_16x16x32_bf16(a, *(const bf16x8*)(wn + k), ah, 0, 0, 0);
                }
                #pragma unroll
                for (int i = 0; i < 4; ++i) {
                    l4[0][wave][lane][i] = ar[i];
                    l4[1][wave][lane][i] = az[i];
                    l4[2][wave][lane][i] = ah[i];
                }
                __syncthreads();
                float sr = l4[0][0][sl][rg] + l4[0][1][sl][rg] + l4[0][2][sl][rg] + l4[0][3][sl][rg];
                float sz = l4[1][0][sl][rg] + l4[1][1][sl][rg] + l4[1][2][sl][rg] + l4[1][3][sl][rg];
                float sh = l4[2][0][sl][rg] + l4[2][1][sl][rg] + l4[2][2][sl][rg] + l4[2][3][sl][rg];
                int b = r0 + erow, m = m0 + ecol;
                const float* gir = gi + (size_t)b * M3;
                float r = sigm(gir[m] + sr + bhh[m]);
                float z = sigm(gir[M + m] + sz + bhh[M + m]);
                float n = tanhf(gir[2 * M + m] + r * (sh + bhh[2 * M + m]));
                size_t hix = (size_t)b * M + m;
                float hv = (1.f - z) * n + z * hf[hix];
                hf[hix] = hv;
                short hbv = (short)f2bf(hv);
                hout[hix] = hbv;
                if (so) so[hix] = hbv;
                gsync(p.bar, ph);
            }
        }
    }

    // ================= decoder =================
    #pragma unroll 1
    for (int t = 0; t < TDEC; ++t) {
        int pin = t & 1, pout = pin ^ 1;
        // ---- stage 1: gru0 (inline softmax of prev logits -> ylds) ----
        {
            int mt = blk & 63, bt = blk >> 6;
            int m0 = mt * 16, r0 = bt * 16;
            if (t == 0) {
                for (int idx = tid; idx < 16 * O_DIM; idx += 256) {
                    int rr = idx >> 9, cc = idx & 511;
                    ylds[rr][cc] = p.yb[(size_t)(r0 + rr) * O_DIM + cc];
                }
            } else {
                const float* lbase = p.out + (size_t)(t - 1) * O_DIM;
                #pragma unroll
                for (int q = 0; q < 4; ++q) {
                    int rr = wave * 4 + q;
                    const float* rowp = lbase + (size_t)(r0 + rr) * (TDEC * O_DIM);
                    float v[8];
                    float mx = -1e30f;
                    #pragma unroll
                    for (int j = 0; j < 8; ++j) { v[j] = rowp[lane * 8 + j]; mx = fmaxf(mx, v[j]); }
                    #pragma unroll
                    for (int off = 32; off > 0; off >>= 1) mx = fmaxf(mx, __shfl_xor(mx, off));
                    float s = 0.f;
                    #pragma unroll
                    for (int j = 0; j < 8; ++j) { v[j] = expf(v[j] - mx); s += v[j]; }
                    #pragma unroll
                    for (int off = 32; off > 0; off >>= 1) s += __shfl_xor(s, off);
                    float inv = 1.f / s;
                    #pragma unroll
                    for (int j = 0; j < 8; ++j) ylds[rr][lane * 8 + j] = (short)f2bf(v[j] * inv);
                }
            }
            __syncthreads();
            floatx4 ar = {0.f,0.f,0.f,0.f}, az = {0.f,0.f,0.f,0.f},
                    ai = {0.f,0.f,0.f,0.f}, ah = {0.f,0.f,0.f,0.f};
            {   // input side from LDS, K=512
                const int Kq = O_DIM >> 2;
                const short* aL = &ylds[lrow][wave * Kq + ko8];
                const short* wr = p.wd_ih0 + (size_t)(m0 + lrow) * O_DIM + wave * Kq + ko8;
                const short* wz = wr + (size_t)M * O_DIM;
                const short* wn = wr + (size_t)2 * M * O_DIM;
                #pragma unroll
                for (int k = 0; k < Kq; k += 32) {
                    bf16x8 a = *(const bf16x8*)(aL + k);
                    ar = __builtin_amdgcn_mfma_f32_16x16x32_bf16(a, *(const bf16x8*)(wr + k), ar, 0, 0, 0);
                    az = __builtin_amdgcn_mfma_f32_16x16x32_bf16(a, *(const bf16x8*)(wz + k), az, 0, 0, 0);
                    ai = __builtin_amdgcn_mfma_f32_16x16x32_bf16(a, *(const bf16x8*)(wn + k), ai, 0, 0, 0);
                }
            }
            {   // hidden side, K=1024
                const int Kq = M >> 2;
                const short* ap = p.h0b + (size_t)pin * B * M + (size_t)(r0 + lrow) * M + wave * Kq + ko8;
                const short* wr = p.wd_hh0 + (size_t)(m0 + lrow) * M + wave * Kq + ko8;
                const short* wz = wr + (size_t)M * M;
                const short* wn = wr + (size_t)2 * M * M;
                #pragma unroll
                for (int k = 0; k < Kq; k += 32) {
                    bf16x8 a = *(const bf16x8*)(ap + k);
                    ar = __builtin_amdgcn_mfma_f32_16x16x32_bf16(a, *(const bf16x8*)(wr + k), ar, 0, 0, 0);
                    az = __builtin_amdgcn_mfma_f32_16x16x32_bf16(a, *(const bf16x8*)(wz + k), az, 0, 0, 0);
                    ah = __builtin_amdgcn_mfma_f32_16x16x32_bf16(a, *(const bf16x8*)(wn + k), ah, 0, 0, 0);
                }
            }
            #pragma unroll
            for (int i = 0; i < 4; ++i) {
                l4[0][wave][lane][i] = ar[i];
                l4[1][wave][lane][i] = az[i];
                l4[2][wave][lane][i] = ai[i];
                l4[3][wave][lane][i] = ah[i];
            }
            __syncthreads();
            float sr = l4[0][0][sl][rg] + l4[0][1][sl][rg] + l4[0][2][sl][rg] + l4[0][3][sl][rg];
            float sz = l4[1][0][sl][rg] + l4[1][1][sl][rg] + l4[1][2][sl][rg] + l4[1][3][sl][rg];
            float si = l4[2][0][sl][rg] + l4[2][1][sl][rg] + l4[2][2][sl][rg] + l4[2][3][sl][rg];
            float sh = l4[3][0][sl][rg] + l4[3][1][sl][rg] + l4[3][2][sl][rg] + l4[3][3][sl][rg];
            int b = r0 + erow, m = m0 + ecol;
            float r = sigm(sr + p.dec_bih0[m] + p.dec_bhh0[m]);
            float z = sigm(sz + p.dec_bih0[M + m] + p.dec_bhh0[M + m]);
            float n = tanhf(si + p.dec_bih0[2 * M + m] + r * (sh + p.dec_bhh0[2 * M + m]));
            size_t hix = (size_t)b * M + m;
            float hv = (1.f - z) * n + z * p.h0f[hix];
            p.h0f[hix] = hv;
            p.h0b[(size_t)pout * B * M + hix] = (short)f2bf(hv);
        }
        gsync(p.bar, ph);
        // ---- stage 2: gru1 ----
        {
            int mt = blk & 63, bt = blk >> 6;
            int m0 = mt * 16, r0 = bt * 16;
            floatx4 ar = {0.f,0.f,0.f,0.f}, az = {0.f,0.f,0.f,0.f},
                    ai = {0.f,0.f,0.f,0.f}, ah = {0.f,0.f,0.f,0.f};
            const int Kq = M >> 2;
            {   // input side: x = h0 output
                const short* ap = p.h0b + (size_t)pout * B * M + (size_t)(r0 + lrow) * M + wave * Kq + ko8;
                const short* wr = p.wd_ih1 + (size_t)(m0 + lrow) * M + wave * Kq + ko8;
                const short* wz = wr + (size_t)M * M;
                const short* wn = wr + (size_t)2 * M * M;
                #pragma unroll
                for (int k = 0; k < Kq; k += 32) {
                    bf16x8 a = *(const bf16x8*)(ap + k);
                    ar = __builtin_amdgcn_mfma_f32_16x16x32_bf16(a, *(const bf16x8*)(wr + k), ar, 0, 0, 0);
                    az = __builtin_amdgcn_mfma_f32_16x16x32_bf16(a, *(const bf16x8*)(wz + k), az, 0, 0, 0);
                    ai = __builtin_amdgcn_mfma_f32_16x16x32_bf16(a, *(const bf16x8*)(wn + k), ai, 0, 0, 0);
                }
            }
            {   // hidden side
                const short* ap = p.h1b + (size_t)pin * B * M + (size_t)(r0 + lrow) * M + wave * Kq + ko8;
                const short* wr = p.wd_hh1 + (size_t)(m0 + lrow) * M + wave * Kq + ko8;
                const short* wz = wr + (size_t)M * M;
                const short* wn = wr + (size_t)2 * M * M;
                #pragma unroll
                for (int k = 0; k < Kq; k += 32) {
                    bf16x8 a = *(const bf16x8*)(ap + k);
                    ar = __builtin_amdgcn_mfma_f32_16x16x32_bf16(a, *(const bf16x8*)(wr + k), ar, 0, 0, 0);
                    az = __builtin_amdgcn_mfma_f32_16x16x32_bf16(a, *(const bf16x8*)(wz + k), az, 0, 0, 0);
                    ah = __builtin_amdgcn_mfma_f32_16x16x32_bf16(a, *(const bf16x8*)(wn + k), ah, 0, 0, 0);
                }
            }
            #pragma unroll
            for (int i = 0; i < 4; ++i) {
                l4[0][wave][lane][i] = ar[i];
                l4[1][wave][lane][i] = az[i];
                l4[2][wave][lane][i] = ai[i];
                l4[3][wave][lane][i] = ah[i];
            }
            __syncthreads();
            float sr = l4[0][0][sl][rg] + l4[0][1][sl][rg] + l4[0][2][sl][rg] + l4[0][3][sl][rg];
            float sz = l4[1][0][sl][rg] + l4[1][1][sl][rg] + l4[1][2][sl][rg] + l4[1][3][sl][rg];
            float si = l4[2][0][sl][rg] + l4[2][1][sl][rg] + l4[2][2][sl][rg] + l4[2][3][sl][rg];
            float sh = l4[3][0][sl][rg] + l4[3][1][sl][rg] + l4[3][2][sl][rg] + l4[3][3][sl][rg];
            int b = r0 + erow, m = m0 + ecol;
            float r = sigm(sr + p.dec_bih1[m] + p.dec_bhh1[m]);
            float z = sigm(sz + p.dec_bih1[M + m] + p.dec_bhh1[M + m]);
            float n = tanhf(si + p.dec_bih1[2 * M + m] + r * (sh + p.dec_bhh1[2 * M + m]));
            size_t hix = (size_t)b * M + m;
            float hv = (1.f - z) * n + z * p.h1f[hix];
            p.h1f[hix] = hv;
            p.h1b[(size_t)pout * B * M + hix] = (short)f2bf(hv);
        }
        gsync(p.bar, ph);
        // ---- stage 3: fc1 (512 tiles, 2 per block, K-split) ----
        {
            const short* Abase = p.h1b + (size_t)pout * B * M;
            const int Kq = M >> 2;
            #pragma unroll
            for (int half = 0; half < 2; ++half) {
                int T = blk + half * 256;
                int ct = T >> 2, rt = T & 3;
                const short* ap = Abase + (size_t)(rt * 16 + lrow) * M + wave * Kq + ko8;
                const short* wp = p.wfc1 + (size_t)(ct * 16 + lrow) * M + wave * Kq + ko8;
                floatx4 acc = {0.f, 0.f, 0.f, 0.f};
                #pragma unroll
                for (int k = 0; k < Kq; k += 32)
                    acc = __builtin_amdgcn_mfma_f32_16x16x32_bf16(
                        *(const bf16x8*)(ap + k), *(const bf16x8*)(wp + k), acc, 0, 0, 0);
                #pragma unroll
                for (int i = 0; i < 4; ++i) l4[half][wave][lane][i] = acc[i];
            }
            __syncthreads();
            #pragma unroll
            for (int half = 0; half < 2; ++half) {
                int T = blk + half * 256;
                int ct = T >> 2, rt = T & 3;
                float s = l4[half][0][sl][rg] + l4[half][1][sl][rg] +
                          l4[half][2][sl][rg] + l4[half][3][sl][rg];
                p.zb[(size_t)(rt * 16 + erow) * LM + ct * 16 + ecol] =
                    s + p.fc1_b[ct * 16 + ecol];
            }
        }
        gsync(p.bar, ph);
        // ---- stage 4: LayerNorm + GELU (64 rows) ----
        if (blk < B) {
            const float* row = p.zb + (size_t)blk * LM;
            float s = 0.f, ss = 0.f;
            for (int i = tid; i < LM; i += 256) { float v = row[i]; s += v; ss += v * v; }
            #pragma unroll
            for (int off = 32; off > 0; off >>= 1) {
                s += __shfl_down(s, off, 64);
                ss += __shfl_down(ss, off, 64);
            }
            if (lane == 0) { redA[wave] = s; redB[wave] = ss; }
            __syncthreads();
            float S = redA[0] + redA[1] + redA[2] + redA[3];
            float SS = redB[0] + redB[1] + redB[2] + redB[3];
            float mu = S * (1.f / LM);
            float var = SS * (1.f / LM) - mu * mu;
            float inv = rsqrtf(var + 1e-5f);
            for (int i = tid; i < LM; i += 256) {
                float v = (row[i] - mu) * inv * p.ln_g[i] + p.ln_b[i];
                float gv = 0.5f * v * (1.f + erff(v * 0.70710678118654752f));
                p.zbb[(size_t)blk * LM + i] = (short)f2bf(gv);
            }
        }
        gsync(p.bar, ph);
        // ---- stage 5: fc2 -> logits (128 tiles, K=2048 split) ----
        if (blk < 128) {
            int ct = blk >> 2, rt = blk & 3;
            const int Kq = LM >> 2;
            const short* ap = p.zbb + (size_t)(rt * 16 + lrow) * LM + wave * Kq + ko8;
            const short* wp = p.wfc2 + (size_t)(ct * 16 + lrow) * LM + wave * Kq + ko8;
            floatx4 acc = {0.f, 0.f, 0.f, 0.f};
            #pragma unroll 4
            for (int k = 0; k < Kq; k += 32)
                acc = __builtin_amdgcn_mfma_f32_16x16x32_bf16(
                    *(const bf16x8*)(ap + k), *(const bf16x8*)(wp + k), acc, 0, 0, 0);
            #pragma unroll
            for (int i = 0; i < 4; ++i) l4[0][wave][lane][i] = acc[i];
            __syncthreads();
            float s = l4[0][0][sl][rg] + l4[0][1][sl][rg] +
                      l4[0][2][sl][rg] + l4[0][3][sl][rg];
            p.out[(size_t)(rt * 16 + erow) * (TDEC * O_DIM) + (size_t)t * O_DIM +
                  ct * 16 + ecol] = s + p.fc2_b[ct * 16 + ecol];
        }
        gsync(p.bar, ph);
    }
}

extern "C" void kernel_launch(void* const* d_in, const int* in_sizes, int n_in,
                              void* d_out, int out_size, void* d_ws, size_t ws_size,
                              hipStream_t stream) {
    const float* X        = (const float*)d_in[0];
    const float* Y0       = (const float*)d_in[1];
    const float* enc_Wih0 = (const float*)d_in[2];
    const float* enc_Whh0 = (const float*)d_in[3];
    const float* enc_bih0 = (const float*)d_in[4];
    const float* enc_bhh0 = (const float*)d_in[5];
    const float* enc_Wih1 = (const float*)d_in[6];
    const float* enc_Whh1 = (const float*)d_in[7];
    const float* enc_bih1 = (const float*)d_in[8];
    const float* enc_bhh1 = (const float*)d_in[9];
    const float* dec_Wih0 = (const float*)d_in[10];
    const float* dec_Whh0 = (const float*)d_in[11];
    const float* dec_bih0 = (const float*)d_in[12];
    const float* dec_bhh0 = (const float*)d_in[13];
    const float* dec_Wih1 = (const float*)d_in[14];
    const float* dec_Whh1 = (const float*)d_in[15];
    const float* dec_bih1 = (const float*)d_in[16];
    const float* dec_bhh1 = (const float*)d_in[17];
    const float* fc1_w    = (const float*)d_in[18];
    const float* fc1_b    = (const float*)d_in[19];
    const float* ln_g     = (const float*)d_in[20];
    const float* ln_b     = (const float*)d_in[21];
    const float* fc2_w    = (const float*)d_in[22];
    const float* fc2_b    = (const float*)d_in[23];
    float* out = (float*)d_out;

    // ---- workspace carve-up ----
    char* wp_ = (char*)d_ws;
    auto carve = [&](size_t bytes) {
        void* r = wp_;
        wp_ += (bytes + 255) & ~(size_t)255;
        return r;
    };
    short* Xt    = (short*)carve((size_t)TIN * B * N_IN * 2);
    short* seqA  = (short*)carve((size_t)TIN * B * M * 2);
    float* gi_ch = (float*)carve((size_t)ECH * B * M3 * 4);     // 12 MB
    short* we_ih0 = (short*)carve((size_t)M3 * N_IN * 2);
    short* we_hh0 = (short*)carve((size_t)M3 * M * 2);
    short* we_ih1 = (short*)carve((size_t)M3 * M * 2);
    short* we_hh1 = (short*)carve((size_t)M3 * M * 2);
    short* wd_ih0 = (short*)carve((size_t)M3 * O_DIM * 2);
    short* wd_hh0 = (short*)carve((size_t)M3 * M * 2);
    short* wd_ih1 = (short*)carve((size_t)M3 * M * 2);
    short* wd_hh1 = (short*)carve((size_t)M3 * M * 2);
    short* wfc1   = (short*)carve((size_t)LM * M * 2);
    short* wfc2   = (short*)carve((size_t)O_DIM * LM * 2);
    float* h0f = (float*)carve((size_t)B * M * 4);
    float* h1f = (float*)carve((size_t)B * M * 4);
    short* h0b = (short*)carve((size_t)2 * B * M * 2);
    short* h1b = (short*)carve((size_t)2 * B * M * 2);
    short* yb  = (short*)carve((size_t)B * O_DIM * 2);
    float* zb  = (float*)carve((size_t)B * LM * 4);
    short* zbb = (short*)carve((size_t)B * LM * 2);
    unsigned* bar = (unsigned*)carve(256);

    auto cast = [&](const float* src, short* dst, int n) {
        cast_bf<<<(n + 255) / 256, 256, 0, stream>>>(src, dst, n);
    };
    cast(enc_Wih0, we_ih0, M3 * N_IN);
    cast(enc_Whh0, we_hh0, M3 * M);
    cast(enc_Wih1, we_ih1, M3 * M);
    cast(enc_Whh1, we_hh1, M3 * M);
    cast(dec_Wih0, wd_ih0, M3 * O_DIM);
    cast(dec_Whh0, wd_hh0, M3 * M);
    cast(dec_Wih1, wd_ih1, M3 * M);
    cast(dec_Whh1, wd_hh1, M3 * M);
    cast(fc1_w, wfc1, LM * M);
    cast(fc2_w, wfc2, O_DIM * LM);
    cast(Y0, yb, B * O_DIM);
    transpose_X_bf<<<(TIN * B * N_IN) / 256, 256, 0, stream>>>(X, Xt);

    hipMemsetAsync(h0f, 0, (size_t)B * M * 4, stream);
    hipMemsetAsync(h1f, 0, (size_t)B * M * 4, stream);
    hipMemsetAsync(h0b, 0, (size_t)B * M * 2, stream);   // parity-0
    hipMemsetAsync(h1b, 0, (size_t)B * M * 2, stream);
    hipMemsetAsync(bar, 0, 256, stream);

    Params hp;
    hp.Xt = Xt; hp.seqA = seqA; hp.gi = gi_ch;
    hp.we_ih0 = we_ih0; hp.we_hh0 = we_hh0; hp.we_ih1 = we_ih1; hp.we_hh1 = we_hh1;
    hp.wd_ih0 = wd_ih0; hp.wd_hh0 = wd_hh0; hp.wd_ih1 = wd_ih1; hp.wd_hh1 = wd_hh1;
    hp.wfc1 = wfc1; hp.wfc2 = wfc2;
    hp.enc_bih0 = enc_bih0; hp.enc_bhh0 = enc_bhh0;
    hp.enc_bih1 = enc_bih1; hp.enc_bhh1 = enc_bhh1;
    hp.dec_bih0 = dec_bih0; hp.dec_bhh0 = dec_bhh0;
    hp.dec_bih1 = dec_bih1; hp.dec_bhh1 = dec_bhh1;
    hp.fc1_b = fc1_b; hp.ln_g = ln_g; hp.ln_b = ln_b; hp.fc2_b = fc2_b;
    hp.h0f = h0f; hp.h1f = h1f; hp.h0b = h0b; hp.h1b = h1b;
    hp.yb = yb; hp.zb = zb; hp.zbb = zbb; hp.out = out;
    hp.bar = bar;

    mega<<<dim3(NBLK), dim3(256), 0, stream>>>(hp);
}

// Round 6
// 12509.824 us; speedup vs baseline: 1.6699x; 1.6699x over previous
//
#include <hip/hip_runtime.h>
#include <math.h>

#define B 64
#define TIN 128
#define N_IN 256
#define M 1024
#define O_DIM 512
#define LM 2048
#define TDEC 64
#define M3 3072
#define ECH 16   // encoder gi timestep chunk
#define NBLK 256

typedef short bf16x8 __attribute__((ext_vector_type(8)));
typedef float floatx4 __attribute__((ext_vector_type(4)));

__device__ __forceinline__ unsigned short f2bf(float f) {
    unsigned int u = __float_as_uint(f);
    u += 0x7FFFu + ((u >> 16) & 1u);      // round-to-nearest-even
    return (unsigned short)(u >> 16);
}
__device__ __forceinline__ float sigm(float x) { return 1.f / (1.f + expf(-x)); }

// hand-rolled grid barrier: monotone counter, all NBLK blocks co-resident.
// KEY: relaxed polls (no per-poll cache invalidate); exactly one release
// fence (L2 writeback) before arrive and one acquire fence (invalidate)
// after the spin exits.
__device__ __forceinline__ void gsync(unsigned* bar, unsigned& phase) {
    __syncthreads();
    if (threadIdx.x == 0) {
        __builtin_amdgcn_fence(__ATOMIC_RELEASE, "agent");   // one wb
        phase += 1;
        __hip_atomic_fetch_add(bar, 1u, __ATOMIC_RELAXED, __HIP_MEMORY_SCOPE_AGENT);
        const unsigned target = phase * NBLK;
        while (__hip_atomic_load(bar, __ATOMIC_RELAXED, __HIP_MEMORY_SCOPE_AGENT) < target)
            __builtin_amdgcn_s_sleep(8);
        __builtin_amdgcn_fence(__ATOMIC_ACQUIRE, "agent");   // one inv
    }
    __syncthreads();
}

// ---------------------------------------------------------------------------
// pre-kernels: casts / transpose
// ---------------------------------------------------------------------------
__global__ __launch_bounds__(256) void cast_bf(const float* __restrict__ in,
                                               short* __restrict__ out, int n) {
    int i = blockIdx.x * 256 + threadIdx.x;
    if (i < n) out[i] = (short)f2bf(in[i]);
}

__global__ __launch_bounds__(256) void transpose_X_bf(const float* __restrict__ X,
                                                      short* __restrict__ Xt) {
    int idx = blockIdx.x * 256 + threadIdx.x;   // t*(B*N) + b*N + n
    int n = idx & (N_IN - 1);
    int b = (idx >> 8) & (B - 1);
    int t = idx >> 14;
    Xt[idx] = (short)f2bf(X[(b * TIN + t) * N_IN + n]);
}

// ---------------------------------------------------------------------------
// megakernel params
// ---------------------------------------------------------------------------
struct Params {
    const short *Xt;
    short *seqA;
    float *gi;                                   // ECH*B*M3 fp32 chunk buffer
    const short *we_ih0, *we_hh0, *we_ih1, *we_hh1;
    const short *wd_ih0, *wd_hh0, *wd_ih1, *wd_hh1, *wfc1, *wfc2;
    const float *enc_bih0, *enc_bhh0, *enc_bih1, *enc_bhh1;
    const float *dec_bih0, *dec_bhh0, *dec_bih1, *dec_bhh1;
    const float *fc1_b, *ln_g, *ln_b, *fc2_b;
    float *h0f, *h1f;
    short *h0b, *h1b;                            // 2x B*M ping-pong each
    const short *yb;                             // Y0 bf16
    float *zb;                                   // B*LM fp32
    short *zbb;                                  // B*LM bf16
    float *out;                                  // d_out logits
    unsigned *bar;                               // grid barrier counter
};

// ---------------------------------------------------------------------------
// One persistent kernel: full encoder + decoder. 256 blocks x 256 threads.
// ---------------------------------------------------------------------------
__global__ __launch_bounds__(256, 1) void mega(Params p) {
    const int blk  = blockIdx.x;
    const int tid  = threadIdx.x;
    const int wave = tid >> 6;
    const int lane = tid & 63;
    const int lrow = lane & 15;
    const int ko8  = (lane >> 4) * 8;
    const int wid  = blk * 4 + wave;            // 0..1023
    // epilogue / reduce thread mapping
    const int erow = tid >> 4, ecol = tid & 15;
    const int sl = (erow >> 2) * 16 + ecol, rg = erow & 3;
    unsigned ph = 0;

    __shared__ float l4[4][4][64][4];           // [gate][wave][lane][i]
    __shared__ short ylds[16][520];             // +8 pad: 2-way banks only
    __shared__ float redA[4], redB[4];

    // ================= encoder =================
    #pragma unroll 1
    for (int layer = 0; layer < 2; ++layer) {
        const short* Wih = layer ? p.we_ih1 : p.we_ih0;
        const short* Whh = layer ? p.we_hh1 : p.we_hh0;
        const float* bih = layer ? p.enc_bih1 : p.enc_bih0;
        const float* bhh = layer ? p.enc_bhh1 : p.enc_bhh0;
        const short* inseq = layer ? p.seqA : p.Xt;
        const int Kin = layer ? M : N_IN;
        float* hf = layer ? p.h1f : p.h0f;
        short* hb = layer ? p.h1b : p.h0b;
        #pragma unroll 1
        for (int c = 0; c < TIN / ECH; ++c) {
            // ---- gi GEMM for ECH steps: rows=ECH*B=1024, cols=3072 ----
            {
                const short* Abase = inseq + (size_t)c * ECH * B * Kin;
                #pragma unroll 1
                for (int T = wid; T < 64 * (M3 / 16); T += 1024) {
                    int rt = T & 63, ct = T >> 6;
                    int r0 = rt * 16, c0 = ct * 16;
                    const short* ap = Abase + (size_t)(r0 + lrow) * Kin + ko8;
                    const short* wp = Wih + (size_t)(c0 + lrow) * Kin + ko8;
                    floatx4 acc = {0.f, 0.f, 0.f, 0.f};
                    #pragma unroll 4
                    for (int k = 0; k < Kin; k += 32)
                        acc = __builtin_amdgcn_mfma_f32_16x16x32_bf16(
                            *(const bf16x8*)(ap + k), *(const bf16x8*)(wp + k),
                            acc, 0, 0, 0);
                    int col = c0 + lrow;
                    float bv = bih[col];
                    int rbase = r0 + (lane >> 4) * 4;
                    #pragma unroll
                    for (int i = 0; i < 4; ++i)
                        p.gi[(size_t)(rbase + i) * M3 + col] = acc[i] + bv;
                }
            }
            gsync(p.bar, ph);
            // ---- ECH sequential GRU steps, one 16x16 tile per block ----
            #pragma unroll 1
            for (int tt = 0; tt < ECH; ++tt) {
                int t = c * ECH + tt;
                int pin = t & 1, pout = pin ^ 1;
                const short* hin = hb + (size_t)pin * B * M;
                short* hout = hb + (size_t)pout * B * M;
                short* so = (layer == 0) ? (p.seqA + (size_t)t * B * M) : nullptr;
                const float* gi = p.gi + (size_t)tt * B * M3;
                int mt = blk & 63, bt = blk >> 6;
                int m0 = mt * 16, r0 = bt * 16;
                const int Kq = M >> 2;
                const short* ap = hin + (size_t)(r0 + lrow) * M + wave * Kq + ko8;
                const short* wr = Whh + (size_t)(m0 + lrow) * M + wave * Kq + ko8;
                const short* wz = wr + (size_t)M * M;
                const short* wn = wr + (size_t)2 * M * M;
                floatx4 ar = {0.f,0.f,0.f,0.f}, az = {0.f,0.f,0.f,0.f},
                        ah = {0.f,0.f,0.f,0.f};
                #pragma unroll
                for (int k = 0; k < Kq; k += 32) {
                    bf16x8 a = *(const bf16x8*)(ap + k);
                    ar = __builtin_amdgcn_mfma_f32_16x16x32_bf16(a, *(const bf16x8*)(wr + k), ar, 0, 0, 0);
                    az = __builtin_amdgcn_mfma_f32_16x16x32_bf16(a, *(const bf16x8*)(wz + k), az, 0, 0, 0);
                    ah = __builtin_amdgcn_mfma_f32_16x16x32_bf16(a, *(const bf16x8*)(wn + k), ah, 0, 0, 0);
                }
                #pragma unroll
                for (int i = 0; i < 4; ++i) {
                    l4[0][wave][lane][i] = ar[i];
                    l4[1][wave][lane][i] = az[i];
                    l4[2][wave][lane][i] = ah[i];
                }
                __syncthreads();
                float sr = l4[0][0][sl][rg] + l4[0][1][sl][rg] + l4[0][2][sl][rg] + l4[0][3][sl][rg];
                float sz = l4[1][0][sl][rg] + l4[1][1][sl][rg] + l4[1][2][sl][rg] + l4[1][3][sl][rg];
                float sh = l4[2][0][sl][rg] + l4[2][1][sl][rg] + l4[2][2][sl][rg] + l4[2][3][sl][rg];
                int b = r0 + erow, m = m0 + ecol;
                const float* gir = gi + (size_t)b * M3;
                float r = sigm(gir[m] + sr + bhh[m]);
                float z = sigm(gir[M + m] + sz + bhh[M + m]);
                float n = tanhf(gir[2 * M + m] + r * (sh + bhh[2 * M + m]));
                size_t hix = (size_t)b * M + m;
                float hv = (1.f - z) * n + z * hf[hix];
                hf[hix] = hv;
                short hbv = (short)f2bf(hv);
                hout[hix] = hbv;
                if (so) so[hix] = hbv;
                gsync(p.bar, ph);
            }
        }
    }

    // ================= decoder =================
    #pragma unroll 1
    for (int t = 0; t < TDEC; ++t) {
        int pin = t & 1, pout = pin ^ 1;
        // ---- stage 1: gru0 (inline softmax of prev logits -> ylds) ----
        {
            int mt = blk & 63, bt = blk >> 6;
            int m0 = mt * 16, r0 = bt * 16;
            if (t == 0) {
                for (int idx = tid; idx < 16 * O_DIM; idx += 256) {
                    int rr = idx >> 9, cc = idx & 511;
                    ylds[rr][cc] = p.yb[(size_t)(r0 + rr) * O_DIM + cc];
                }
            } else {
                const float* lbase = p.out + (size_t)(t - 1) * O_DIM;
                #pragma unroll
                for (int q = 0; q < 4; ++q) {
                    int rr = wave * 4 + q;
                    const float* rowp = lbase + (size_t)(r0 + rr) * (TDEC * O_DIM);
                    float v[8];
                    float mx = -1e30f;
                    #pragma unroll
                    for (int j = 0; j < 8; ++j) { v[j] = rowp[lane * 8 + j]; mx = fmaxf(mx, v[j]); }
                    #pragma unroll
                    for (int off = 32; off > 0; off >>= 1) mx = fmaxf(mx, __shfl_xor(mx, off));
                    float s = 0.f;
                    #pragma unroll
                    for (int j = 0; j < 8; ++j) { v[j] = expf(v[j] - mx); s += v[j]; }
                    #pragma unroll
                    for (int off = 32; off > 0; off >>= 1) s += __shfl_xor(s, off);
                    float inv = 1.f / s;
                    #pragma unroll
                    for (int j = 0; j < 8; ++j) ylds[rr][lane * 8 + j] = (short)f2bf(v[j] * inv);
                }
            }
            __syncthreads();
            floatx4 ar = {0.f,0.f,0.f,0.f}, az = {0.f,0.f,0.f,0.f},
                    ai = {0.f,0.f,0.f,0.f}, ah = {0.f,0.f,0.f,0.f};
            {   // input side from LDS, K=512
                const int Kq = O_DIM >> 2;
                const short* aL = &ylds[lrow][wave * Kq + ko8];
                const short* wr = p.wd_ih0 + (size_t)(m0 + lrow) * O_DIM + wave * Kq + ko8;
                const short* wz = wr + (size_t)M * O_DIM;
                const short* wn = wr + (size_t)2 * M * O_DIM;
                #pragma unroll
                for (int k = 0; k < Kq; k += 32) {
                    bf16x8 a = *(const bf16x8*)(aL + k);
                    ar = __builtin_amdgcn_mfma_f32_16x16x32_bf16(a, *(const bf16x8*)(wr + k), ar, 0, 0, 0);
                    az = __builtin_amdgcn_mfma_f32_16x16x32_bf16(a, *(const bf16x8*)(wz + k), az, 0, 0, 0);
                    ai = __builtin_amdgcn_mfma_f32_16x16x32_bf16(a, *(const bf16x8*)(wn + k), ai, 0, 0, 0);
                }
            }
            {   // hidden side, K=1024
                const int Kq = M >> 2;
                const short* ap = p.h0b + (size_t)pin * B * M + (size_t)(r0 + lrow) * M + wave * Kq + ko8;
                const short* wr = p.wd_hh0 + (size_t)(m0 + lrow) * M + wave * Kq + ko8;
                const short* wz = wr + (size_t)M * M;
                const short* wn = wr + (size_t)2 * M * M;
                #pragma unroll
                for (int k = 0; k < Kq; k += 32) {
                    bf16x8 a = *(const bf16x8*)(ap + k);
                    ar = __builtin_amdgcn_mfma_f32_16x16x32_bf16(a, *(const bf16x8*)(wr + k), ar, 0, 0, 0);
                    az = __builtin_amdgcn_mfma_f32_16x16x32_bf16(a, *(const bf16x8*)(wz + k), az, 0, 0, 0);
                    ah = __builtin_amdgcn_mfma_f32_16x16x32_bf16(a, *(const bf16x8*)(wn + k), ah, 0, 0, 0);
                }
            }
            #pragma unroll
            for (int i = 0; i < 4; ++i) {
                l4[0][wave][lane][i] = ar[i];
                l4[1][wave][lane][i] = az[i];
                l4[2][wave][lane][i] = ai[i];
                l4[3][wave][lane][i] = ah[i];
            }
            __syncthreads();
            float sr = l4[0][0][sl][rg] + l4[0][1][sl][rg] + l4[0][2][sl][rg] + l4[0][3][sl][rg];
            float sz = l4[1][0][sl][rg] + l4[1][1][sl][rg] + l4[1][2][sl][rg] + l4[1][3][sl][rg];
            float si = l4[2][0][sl][rg] + l4[2][1][sl][rg] + l4[2][2][sl][rg] + l4[2][3][sl][rg];
            float sh = l4[3][0][sl][rg] + l4[3][1][sl][rg] + l4[3][2][sl][rg] + l4[3][3][sl][rg];
            int b = r0 + erow, m = m0 + ecol;
            float r = sigm(sr + p.dec_bih0[m] + p.dec_bhh0[m]);
            float z = sigm(sz + p.dec_bih0[M + m] + p.dec_bhh0[M + m]);
            float n = tanhf(si + p.dec_bih0[2 * M + m] + r * (sh + p.dec_bhh0[2 * M + m]));
            size_t hix = (size_t)b * M + m;
            float hv = (1.f - z) * n + z * p.h0f[hix];
            p.h0f[hix] = hv;
            p.h0b[(size_t)pout * B * M + hix] = (short)f2bf(hv);
        }
        gsync(p.bar, ph);
        // ---- stage 2: gru1 ----
        {
            int mt = blk & 63, bt = blk >> 6;
            int m0 = mt * 16, r0 = bt * 16;
            floatx4 ar = {0.f,0.f,0.f,0.f}, az = {0.f,0.f,0.f,0.f},
                    ai = {0.f,0.f,0.f,0.f}, ah = {0.f,0.f,0.f,0.f};
            const int Kq = M >> 2;
            {   // input side: x = h0 output
                const short* ap = p.h0b + (size_t)pout * B * M + (size_t)(r0 + lrow) * M + wave * Kq + ko8;
                const short* wr = p.wd_ih1 + (size_t)(m0 + lrow) * M + wave * Kq + ko8;
                const short* wz = wr + (size_t)M * M;
                const short* wn = wr + (size_t)2 * M * M;
                #pragma unroll
                for (int k = 0; k < Kq; k += 32) {
                    bf16x8 a = *(const bf16x8*)(ap + k);
                    ar = __builtin_amdgcn_mfma_f32_16x16x32_bf16(a, *(const bf16x8*)(wr + k), ar, 0, 0, 0);
                    az = __builtin_amdgcn_mfma_f32_16x16x32_bf16(a, *(const bf16x8*)(wz + k), az, 0, 0, 0);
                    ai = __builtin_amdgcn_mfma_f32_16x16x32_bf16(a, *(const bf16x8*)(wn + k), ai, 0, 0, 0);
                }
            }
            {   // hidden side
                const short* ap = p.h1b + (size_t)pin * B * M + (size_t)(r0 + lrow) * M + wave * Kq + ko8;
                const short* wr = p.wd_hh1 + (size_t)(m0 + lrow) * M + wave * Kq + ko8;
                const short* wz = wr + (size_t)M * M;
                const short* wn = wr + (size_t)2 * M * M;
                #pragma unroll
                for (int k = 0; k < Kq; k += 32) {
                    bf16x8 a = *(const bf16x8*)(ap + k);
                    ar = __builtin_amdgcn_mfma_f32_16x16x32_bf16(a, *(const bf16x8*)(wr + k), ar, 0, 0, 0);
                    az = __builtin_amdgcn_mfma_f32_16x16x32_bf16(a, *(const bf16x8*)(wz + k), az, 0, 0, 0);
                    ah = __builtin_amdgcn_mfma_f32_16x16x32_bf16(a, *(const bf16x8*)(wn + k), ah, 0, 0, 0);
                }
            }
            #pragma unroll
            for (int i = 0; i < 4; ++i) {
                l4[0][wave][lane][i] = ar[i];
                l4[1][wave][lane][i] = az[i];
                l4[2][wave][lane][i] = ai[i];
                l4[3][wave][lane][i] = ah[i];
            }
            __syncthreads();
            float sr = l4[0][0][sl][rg] + l4[0][1][sl][rg] + l4[0][2][sl][rg] + l4[0][3][sl][rg];
            float sz = l4[1][0][sl][rg] + l4[1][1][sl][rg] + l4[1][2][sl][rg] + l4[1][3][sl][rg];
            float si = l4[2][0][sl][rg] + l4[2][1][sl][rg] + l4[2][2][sl][rg] + l4[2][3][sl][rg];
            float sh = l4[3][0][sl][rg] + l4[3][1][sl][rg] + l4[3][2][sl][rg] + l4[3][3][sl][rg];
            int b = r0 + erow, m = m0 + ecol;
            float r = sigm(sr + p.dec_bih1[m] + p.dec_bhh1[m]);
            float z = sigm(sz + p.dec_bih1[M + m] + p.dec_bhh1[M + m]);
            float n = tanhf(si + p.dec_bih1[2 * M + m] + r * (sh + p.dec_bhh1[2 * M + m]));
            size_t hix = (size_t)b * M + m;
            float hv = (1.f - z) * n + z * p.h1f[hix];
            p.h1f[hix] = hv;
            p.h1b[(size_t)pout * B * M + hix] = (short)f2bf(hv);
        }
        gsync(p.bar, ph);
        // ---- stage 3: fc1 (512 tiles, 2 per block, K-split) ----
        {
            const short* Abase = p.h1b + (size_t)pout * B * M;
            const int Kq = M >> 2;
            #pragma unroll
            for (int half = 0; half < 2; ++half) {
                int T = blk + half * 256;
                int ct = T >> 2, rt = T & 3;
                const short* ap = Abase + (size_t)(rt * 16 + lrow) * M + wave * Kq + ko8;
                const short* wp = p.wfc1 + (size_t)(ct * 16 + lrow) * M + wave * Kq + ko8;
                floatx4 acc = {0.f, 0.f, 0.f, 0.f};
                #pragma unroll
                for (int k = 0; k < Kq; k += 32)
                    acc = __builtin_amdgcn_mfma_f32_16x16x32_bf16(
                        *(const bf16x8*)(ap + k), *(const bf16x8*)(wp + k), acc, 0, 0, 0);
                #pragma unroll
                for (int i = 0; i < 4; ++i) l4[half][wave][lane][i] = acc[i];
            }
            __syncthreads();
            #pragma unroll
            for (int half = 0; half < 2; ++half) {
                int T = blk + half * 256;
                int ct = T >> 2, rt = T & 3;
                float s = l4[half][0][sl][rg] + l4[half][1][sl][rg] +
                          l4[half][2][sl][rg] + l4[half][3][sl][rg];
                p.zb[(size_t)(rt * 16 + erow) * LM + ct * 16 + ecol] =
                    s + p.fc1_b[ct * 16 + ecol];
            }
        }
        gsync(p.bar, ph);
        // ---- stage 4: LayerNorm + GELU (64 rows) ----
        if (blk < B) {
            const float* row = p.zb + (size_t)blk * LM;
            float s = 0.f, ss = 0.f;
            for (int i = tid; i < LM; i += 256) { float v = row[i]; s += v; ss += v * v; }
            #pragma unroll
            for (int off = 32; off > 0; off >>= 1) {
                s += __shfl_down(s, off, 64);
                ss += __shfl_down(ss, off, 64);
            }
            if (lane == 0) { redA[wave] = s; redB[wave] = ss; }
            __syncthreads();
            float S = redA[0] + redA[1] + redA[2] + redA[3];
            float SS = redB[0] + redB[1] + redB[2] + redB[3];
            float mu = S * (1.f / LM);
            float var = SS * (1.f / LM) - mu * mu;
            float inv = rsqrtf(var + 1e-5f);
            for (int i = tid; i < LM; i += 256) {
                float v = (row[i] - mu) * inv * p.ln_g[i] + p.ln_b[i];
                float gv = 0.5f * v * (1.f + erff(v * 0.70710678118654752f));
                p.zbb[(size_t)blk * LM + i] = (short)f2bf(gv);
            }
        }
        gsync(p.bar, ph);
        // ---- stage 5: fc2 -> logits (128 tiles, K=2048 split) ----
        if (blk < 128) {
            int ct = blk >> 2, rt = blk & 3;
            const int Kq = LM >> 2;
            const short* ap = p.zbb + (size_t)(rt * 16 + lrow) * LM + wave * Kq + ko8;
            const short* wp = p.wfc2 + (size_t)(ct * 16 + lrow) * LM + wave * Kq + ko8;
            floatx4 acc = {0.f, 0.f, 0.f, 0.f};
            #pragma unroll 4
            for (int k = 0; k < Kq; k += 32)
                acc = __builtin_amdgcn_mfma_f32_16x16x32_bf16(
                    *(const bf16x8*)(ap + k), *(const bf16x8*)(wp + k), acc, 0, 0, 0);
            #pragma unroll
            for (int i = 0; i < 4; ++i) l4[0][wave][lane][i] = acc[i];
            __syncthreads();
            float s = l4[0][0][sl][rg] + l4[0][1][sl][rg] +
                      l4[0][2][sl][rg] + l4[0][3][sl][rg];
            p.out[(size_t)(rt * 16 + erow) * (TDEC * O_DIM) + (size_t)t * O_DIM +
                  ct * 16 + ecol] = s + p.fc2_b[ct * 16 + ecol];
        }
        gsync(p.bar, ph);
    }
}

extern "C" void kernel_launch(void* const* d_in, const int* in_sizes, int n_in,
                              void* d_out, int out_size, void* d_ws, size_t ws_size,
                              hipStream_t stream) {
    const float* X        = (const float*)d_in[0];
    const float* Y0       = (const float*)d_in[1];
    const float* enc_Wih0 = (const float*)d_in[2];
    const float* enc_Whh0 = (const float*)d_in[3];
    const float* enc_bih0 = (const float*)d_in[4];
    const float* enc_bhh0 = (const float*)d_in[5];
    const float* enc_Wih1 = (const float*)d_in[6];
    const float* enc_Whh1 = (const float*)d_in[7];
    const float* enc_bih1 = (const float*)d_in[8];
    const float* enc_bhh1 = (const float*)d_in[9];
    const float* dec_Wih0 = (const float*)d_in[10];
    const float* dec_Whh0 = (const float*)d_in[11];
    const float* dec_bih0 = (const float*)d_in[12];
    const float* dec_bhh0 = (const float*)d_in[13];
    const float* dec_Wih1 = (const float*)d_in[14];
    const float* dec_Whh1 = (const float*)d_in[15];
    const float* dec_bih1 = (const float*)d_in[16];
    const float* dec_bhh1 = (const float*)d_in[17];
    const float* fc1_w    = (const float*)d_in[18];
    const float* fc1_b    = (const float*)d_in[19];
    const float* ln_g     = (const float*)d_in[20];
    const float* ln_b     = (const float*)d_in[21];
    const float* fc2_w    = (const float*)d_in[22];
    const float* fc2_b    = (const float*)d_in[23];
    float* out = (float*)d_out;

    // ---- workspace carve-up ----
    char* wp_ = (char*)d_ws;
    auto carve = [&](size_t bytes) {
        void* r = wp_;
        wp_ += (bytes + 255) & ~(size_t)255;
        return r;
    };
    short* Xt    = (short*)carve((size_t)TIN * B * N_IN * 2);
    short* seqA  = (short*)carve((size_t)TIN * B * M * 2);
    float* gi_ch = (float*)carve((size_t)ECH * B * M3 * 4);     // 12 MB
    short* we_ih0 = (short*)carve((size_t)M3 * N_IN * 2);
    short* we_hh0 = (short*)carve((size_t)M3 * M * 2);
    short* we_ih1 = (short*)carve((size_t)M3 * M * 2);
    short* we_hh1 = (short*)carve((size_t)M3 * M * 2);
    short* wd_ih0 = (short*)carve((size_t)M3 * O_DIM * 2);
    short* wd_hh0 = (short*)carve((size_t)M3 * M * 2);
    short* wd_ih1 = (short*)carve((size_t)M3 * M * 2);
    short* wd_hh1 = (short*)carve((size_t)M3 * M * 2);
    short* wfc1   = (short*)carve((size_t)LM * M * 2);
    short* wfc2   = (short*)carve((size_t)O_DIM * LM * 2);
    float* h0f = (float*)carve((size_t)B * M * 4);
    float* h1f = (float*)carve((size_t)B * M * 4);
    short* h0b = (short*)carve((size_t)2 * B * M * 2);
    short* h1b = (short*)carve((size_t)2 * B * M * 2);
    short* yb  = (short*)carve((size_t)B * O_DIM * 2);
    float* zb  = (float*)carve((size_t)B * LM * 4);
    short* zbb = (short*)carve((size_t)B * LM * 2);
    unsigned* bar = (unsigned*)carve(256);

    auto cast = [&](const float* src, short* dst, int n) {
        cast_bf<<<(n + 255) / 256, 256, 0, stream>>>(src, dst, n);
    };
    cast(enc_Wih0, we_ih0, M3 * N_IN);
    cast(enc_Whh0, we_hh0, M3 * M);
    cast(enc_Wih1, we_ih1, M3 * M);
    cast(enc_Whh1, we_hh1, M3 * M);
    cast(dec_Wih0, wd_ih0, M3 * O_DIM);
    cast(dec_Whh0, wd_hh0, M3 * M);
    cast(dec_Wih1, wd_ih1, M3 * M);
    cast(dec_Whh1, wd_hh1, M3 * M);
    cast(fc1_w, wfc1, LM * M);
    cast(fc2_w, wfc2, O_DIM * LM);
    cast(Y0, yb, B * O_DIM);
    transpose_X_bf<<<(TIN * B * N_IN) / 256, 256, 0, stream>>>(X, Xt);

    hipMemsetAsync(h0f, 0, (size_t)B * M * 4, stream);
    hipMemsetAsync(h1f, 0, (size_t)B * M * 4, stream);
    hipMemsetAsync(h0b, 0, (size_t)B * M * 2, stream);   // parity-0
    hipMemsetAsync(h1b, 0, (size_t)B * M * 2, stream);
    hipMemsetAsync(bar, 0, 256, stream);

    Params hp;
    hp.Xt = Xt; hp.seqA = seqA; hp.gi = gi_ch;
    hp.we_ih0 = we_ih0; hp.we_hh0 = we_hh0; hp.we_ih1 = we_ih1; hp.we_hh1 = we_hh1;
    hp.wd_ih0 = wd_ih0; hp.wd_hh0 = wd_hh0; hp.wd_ih1 = wd_ih1; hp.wd_hh1 = wd_hh1;
    hp.wfc1 = wfc1; hp.wfc2 = wfc2;
    hp.enc_bih0 = enc_bih0; hp.enc_bhh0 = enc_bhh0;
    hp.enc_bih1 = enc_bih1; hp.enc_bhh1 = enc_bhh1;
    hp.dec_bih0 = dec_bih0; hp.dec_bhh0 = dec_bhh0;
    hp.dec_bih1 = dec_bih1; hp.dec_bhh1 = dec_bhh1;
    hp.fc1_b = fc1_b; hp.ln_g = ln_g; hp.ln_b = ln_b; hp.fc2_b = fc2_b;
    hp.h0f = h0f; hp.h1f = h1f; hp.h0b = h0b; hp.h1b = h1b;
    hp.yb = yb; hp.zb = zb; hp.zbb = zbb; hp.out = out;
    hp.bar = bar;

    mega<<<dim3(NBLK), dim3(256), 0, stream>>>(hp);
}

// Round 7
// 8499.451 us; speedup vs baseline: 2.4578x; 1.4718x over previous
//
#include <hip/hip_runtime.h>
#include <math.h>

#define B 64
#define TIN 128
#define N_IN 256
#define M 1024
#define O_DIM 512
#define LM 2048
#define TDEC 64
#define M3 3072
#define ECH 16   // encoder gi timestep chunk
#define NBLK 256

typedef short bf16x8 __attribute__((ext_vector_type(8)));
typedef float floatx4 __attribute__((ext_vector_type(4)));
typedef unsigned long long u64t;

__device__ __forceinline__ unsigned short f2bf(float f) {
    unsigned int u = __float_as_uint(f);
    u += 0x7FFFu + ((u >> 16) & 1u);      // round-to-nearest-even
    return (unsigned short)(u >> 16);
}
__device__ __forceinline__ float sigm(float x) { return 1.f / (1.f + expf(-x)); }

// ---- coherent (agent-scope, L2-bypassing) access helpers -------------------
// relaxed atomics compile to global_load/store with sc bits: they read/write
// the coherence point (L3) directly, so NO barrier fences (wbl2/inv) needed.
__device__ __forceinline__ u64t cload_u64(const void* p) {
    return __hip_atomic_load((const u64t*)p, __ATOMIC_RELAXED, __HIP_MEMORY_SCOPE_AGENT);
}
__device__ __forceinline__ float2 cload_f2(const float* p) {
    union { u64t u; float2 f; } c; c.u = cload_u64(p); return c.f;
}
__device__ __forceinline__ float cloadf(const float* p) {
    union { unsigned u; float f; } c;
    c.u = __hip_atomic_load((const unsigned*)p, __ATOMIC_RELAXED, __HIP_MEMORY_SCOPE_AGENT);
    return c.f;
}
__device__ __forceinline__ void cstoref(float* p, float v) {
    union { unsigned u; float f; } c; c.f = v;
    __hip_atomic_store((unsigned*)p, c.u, __ATOMIC_RELAXED, __HIP_MEMORY_SCOPE_AGENT);
}
__device__ __forceinline__ void cstoreu(unsigned* p, unsigned v) {
    __hip_atomic_store(p, v, __ATOMIC_RELAXED, __HIP_MEMORY_SCOPE_AGENT);
}
__device__ __forceinline__ bf16x8 cload16(const short* p) {
    union { u64t u[2]; bf16x8 v; } c;
    c.u[0] = cload_u64(p);
    c.u[1] = cload_u64(p + 4);
    return c.v;
}

// grid barrier: NO cache-maintenance fences. __syncthreads drains each
// thread's vmcnt (write-through stores are then globally visible); arrive +
// poll are relaxed agent atomics (coherent by construction).
__device__ __forceinline__ void gsync(unsigned* bar, unsigned& phase) {
    __syncthreads();
    if (threadIdx.x == 0) {
        asm volatile("s_waitcnt vmcnt(0)" ::: "memory");
        phase += 1;
        __hip_atomic_fetch_add(bar, 1u, __ATOMIC_RELAXED, __HIP_MEMORY_SCOPE_AGENT);
        const unsigned target = phase * NBLK;
        while (__hip_atomic_load(bar, __ATOMIC_RELAXED, __HIP_MEMORY_SCOPE_AGENT) < target)
            __builtin_amdgcn_s_sleep(4);
    }
    __syncthreads();
}

// ---------------------------------------------------------------------------
// pre-kernels: casts / transpose
// ---------------------------------------------------------------------------
__global__ __launch_bounds__(256) void cast_bf(const float* __restrict__ in,
                                               short* __restrict__ out, int n) {
    int i = blockIdx.x * 256 + threadIdx.x;
    if (i < n) out[i] = (short)f2bf(in[i]);
}

__global__ __launch_bounds__(256) void transpose_X_bf(const float* __restrict__ X,
                                                      short* __restrict__ Xt) {
    int idx = blockIdx.x * 256 + threadIdx.x;   // t*(B*N) + b*N + n
    int n = idx & (N_IN - 1);
    int b = (idx >> 8) & (B - 1);
    int t = idx >> 14;
    Xt[idx] = (short)f2bf(X[(b * TIN + t) * N_IN + n]);
}

// ---------------------------------------------------------------------------
// megakernel params
// ---------------------------------------------------------------------------
struct Params {
    const short *Xt;
    short *seqA;
    float *gi;                                   // ECH*B*M3 fp32 chunk buffer
    const short *we_ih0, *we_hh0, *we_ih1, *we_hh1;
    const short *wd_ih0, *wd_hh0, *wd_ih1, *wd_hh1, *wfc1, *wfc2;
    const float *enc_bih0, *enc_bhh0, *enc_bih1, *enc_bhh1;
    const float *dec_bih0, *dec_bhh0, *dec_bih1, *dec_bhh1;
    const float *fc1_b, *ln_g, *ln_b, *fc2_b;
    float *h0f, *h1f;
    short *h0b, *h1b;                            // 2x B*M ping-pong each
    const short *yb;                             // Y0 bf16
    float *zb;                                   // B*LM fp32
    short *zbb;                                  // B*LM bf16
    float *out;                                  // d_out logits
    unsigned *bar;                               // grid barrier counter
};

// ---------------------------------------------------------------------------
// One persistent kernel: full encoder + decoder. 256 blocks x 256 threads.
// ---------------------------------------------------------------------------
__global__ __launch_bounds__(256, 1) void mega(Params p) {
    const int blk  = blockIdx.x;
    const int tid  = threadIdx.x;
    const int wave = tid >> 6;
    const int lane = tid & 63;
    const int lrow = lane & 15;
    const int ko8  = (lane >> 4) * 8;
    const int wid  = blk * 4 + wave;            // 0..1023
    // epilogue / reduce thread mapping
    const int erow = tid >> 4, ecol = tid & 15;
    const int sl = (erow >> 2) * 16 + ecol, rg = erow & 3;
    unsigned ph = 0;

    __shared__ float l4[4][4][64][4];           // [gate][wave][lane][i]
    __shared__ short ylds[16][520];             // +8 pad: 2-way banks only
    __shared__ float redA[4], redB[4];

    // ================= encoder =================
    #pragma unroll 1
    for (int layer = 0; layer < 2; ++layer) {
        const bool lay1 = (layer == 1);
        const short* Wih = lay1 ? p.we_ih1 : p.we_ih0;
        const short* Whh = lay1 ? p.we_hh1 : p.we_hh0;
        const float* bih = lay1 ? p.enc_bih1 : p.enc_bih0;
        const float* bhh = lay1 ? p.enc_bhh1 : p.enc_bhh0;
        const short* inseq = lay1 ? p.seqA : p.Xt;
        const int Kin = lay1 ? M : N_IN;
        float* hf = lay1 ? p.h1f : p.h0f;
        short* hb = lay1 ? p.h1b : p.h0b;
        #pragma unroll 1
        for (int c = 0; c < TIN / ECH; ++c) {
            // ---- gi GEMM for ECH steps: rows=ECH*B=1024, cols=3072 ----
            {
                const short* Abase = inseq + (size_t)c * ECH * B * Kin;
                #pragma unroll 1
                for (int T = wid; T < 64 * (M3 / 16); T += 1024) {
                    int rt = T & 63, ct = T >> 6;
                    int r0 = rt * 16, c0 = ct * 16;
                    const short* ap = Abase + (size_t)(r0 + lrow) * Kin + ko8;
                    const short* wp = Wih + (size_t)(c0 + lrow) * Kin + ko8;
                    floatx4 acc = {0.f, 0.f, 0.f, 0.f};
                    #pragma unroll 4
                    for (int k = 0; k < Kin; k += 32) {
                        bf16x8 a = lay1 ? cload16(ap + k)
                                        : *(const bf16x8*)(ap + k);
                        acc = __builtin_amdgcn_mfma_f32_16x16x32_bf16(
                            a, *(const bf16x8*)(wp + k), acc, 0, 0, 0);
                    }
                    int col = c0 + lrow;
                    float bv = bih[col];
                    int rbase = r0 + (lane >> 4) * 4;
                    #pragma unroll
                    for (int i = 0; i < 4; ++i)
                        cstoref(&p.gi[(size_t)(rbase + i) * M3 + col], acc[i] + bv);
                }
            }
            gsync(p.bar, ph);
            // ---- ECH sequential GRU steps, one 16x16 tile per block ----
            #pragma unroll 1
            for (int tt = 0; tt < ECH; ++tt) {
                int t = c * ECH + tt;
                int pin = t & 1, pout = pin ^ 1;
                const short* hin = hb + (size_t)pin * B * M;
                short* hout = hb + (size_t)pout * B * M;
                short* so = (layer == 0) ? (p.seqA + (size_t)t * B * M) : nullptr;
                const float* gi = p.gi + (size_t)tt * B * M3;
                int mt = blk & 63, bt = blk >> 6;
                int m0 = mt * 16, r0 = bt * 16;
                const int Kq = M >> 2;
                const short* ap = hin + (size_t)(r0 + lrow) * M + wave * Kq + ko8;
                const short* wr = Whh + (size_t)(m0 + lrow) * M + wave * Kq + ko8;
                const short* wz = wr + (size_t)M * M;
                const short* wn = wr + (size_t)2 * M * M;
                floatx4 ar = {0.f,0.f,0.f,0.f}, az = {0.f,0.f,0.f,0.f},
                        ah = {0.f,0.f,0.f,0.f};
                #pragma unroll
                for (int k = 0; k < Kq; k += 32) {
                    bf16x8 a = cload16(ap + k);
                    ar = __builtin_amdgcn_mfma_f32_16x16x32_bf16(a, *(const bf16x8*)(wr + k), ar, 0, 0, 0);
                    az = __builtin_amdgcn_mfma_f32_16x16x32_bf16(a, *(const bf16x8*)(wz + k), az, 0, 0, 0);
                    ah = __builtin_amdgcn_mfma_f32_16x16x32_bf16(a, *(const bf16x8*)(wn + k), ah, 0, 0, 0);
                }
                #pragma unroll
                for (int i = 0; i < 4; ++i) {
                    l4[0][wave][lane][i] = ar[i];
                    l4[1][wave][lane][i] = az[i];
                    l4[2][wave][lane][i] = ah[i];
                }
                __syncthreads();
                float sr = l4[0][0][sl][rg] + l4[0][1][sl][rg] + l4[0][2][sl][rg] + l4[0][3][sl][rg];
                float sz = l4[1][0][sl][rg] + l4[1][1][sl][rg] + l4[1][2][sl][rg] + l4[1][3][sl][rg];
                float sh = l4[2][0][sl][rg] + l4[2][1][sl][rg] + l4[2][2][sl][rg] + l4[2][3][sl][rg];
                int b = r0 + erow, m = m0 + ecol;
                const float* gir = gi + (size_t)b * M3;
                float r = sigm(cloadf(gir + m) + sr + bhh[m]);
                float z = sigm(cloadf(gir + M + m) + sz + bhh[M + m]);
                float n = tanhf(cloadf(gir + 2 * M + m) + r * (sh + bhh[2 * M + m]));
                size_t hix = (size_t)b * M + m;
                float hv = (1.f - z) * n + z * hf[hix];
                hf[hix] = hv;
                unsigned hbits = f2bf(hv);
                unsigned up = __shfl_down(hbits, 1);
                if (!(tid & 1)) {
                    unsigned packed = hbits | (up << 16);
                    cstoreu((unsigned*)(hout + hix), packed);
                    if (so) cstoreu((unsigned*)(so + hix), packed);
                }
                gsync(p.bar, ph);
            }
        }
    }

    // ================= decoder =================
    #pragma unroll 1
    for (int t = 0; t < TDEC; ++t) {
        int pin = t & 1, pout = pin ^ 1;
        // ---- stage 1: gru0 (inline softmax of prev logits -> ylds) ----
        {
            int mt = blk & 63, bt = blk >> 6;
            int m0 = mt * 16, r0 = bt * 16;
            if (t == 0) {
                for (int idx = tid; idx < 16 * O_DIM; idx += 256) {
                    int rr = idx >> 9, cc = idx & 511;
                    ylds[rr][cc] = p.yb[(size_t)(r0 + rr) * O_DIM + cc];
                }
            } else {
                const float* lbase = p.out + (size_t)(t - 1) * O_DIM;
                #pragma unroll
                for (int q = 0; q < 4; ++q) {
                    int rr = wave * 4 + q;
                    const float* rowp = lbase + (size_t)(r0 + rr) * (TDEC * O_DIM);
                    float v[8];
                    float mx = -1e30f;
                    #pragma unroll
                    for (int j2 = 0; j2 < 4; ++j2) {
                        float2 two = cload_f2(rowp + lane * 8 + j2 * 2);
                        v[j2 * 2] = two.x; v[j2 * 2 + 1] = two.y;
                        mx = fmaxf(mx, fmaxf(two.x, two.y));
                    }
                    #pragma unroll
                    for (int off = 32; off > 0; off >>= 1) mx = fmaxf(mx, __shfl_xor(mx, off));
                    float s = 0.f;
                    #pragma unroll
                    for (int j = 0; j < 8; ++j) { v[j] = expf(v[j] - mx); s += v[j]; }
                    #pragma unroll
                    for (int off = 32; off > 0; off >>= 1) s += __shfl_xor(s, off);
                    float inv = 1.f / s;
                    #pragma unroll
                    for (int j = 0; j < 8; ++j) ylds[rr][lane * 8 + j] = (short)f2bf(v[j] * inv);
                }
            }
            __syncthreads();
            floatx4 ar = {0.f,0.f,0.f,0.f}, az = {0.f,0.f,0.f,0.f},
                    ai = {0.f,0.f,0.f,0.f}, ah = {0.f,0.f,0.f,0.f};
            {   // input side from LDS, K=512
                const int Kq = O_DIM >> 2;
                const short* aL = &ylds[lrow][wave * Kq + ko8];
                const short* wr = p.wd_ih0 + (size_t)(m0 + lrow) * O_DIM + wave * Kq + ko8;
                const short* wz = wr + (size_t)M * O_DIM;
                const short* wn = wr + (size_t)2 * M * O_DIM;
                #pragma unroll
                for (int k = 0; k < Kq; k += 32) {
                    bf16x8 a = *(const bf16x8*)(aL + k);
                    ar = __builtin_amdgcn_mfma_f32_16x16x32_bf16(a, *(const bf16x8*)(wr + k), ar, 0, 0, 0);
                    az = __builtin_amdgcn_mfma_f32_16x16x32_bf16(a, *(const bf16x8*)(wz + k), az, 0, 0, 0);
                    ai = __builtin_amdgcn_mfma_f32_16x16x32_bf16(a, *(const bf16x8*)(wn + k), ai, 0, 0, 0);
                }
            }
            {   // hidden side, K=1024
                const int Kq = M >> 2;
                const short* ap = p.h0b + (size_t)pin * B * M + (size_t)(r0 + lrow) * M + wave * Kq + ko8;
                const short* wr = p.wd_hh0 + (size_t)(m0 + lrow) * M + wave * Kq + ko8;
                const short* wz = wr + (size_t)M * M;
                const short* wn = wr + (size_t)2 * M * M;
                #pragma unroll
                for (int k = 0; k < Kq; k += 32) {
                    bf16x8 a = cload16(ap + k);
                    ar = __builtin_amdgcn_mfma_f32_16x16x32_bf16(a, *(const bf16x8*)(wr + k), ar, 0, 0, 0);
                    az = __builtin_amdgcn_mfma_f32_16x16x32_bf16(a, *(const bf16x8*)(wz + k), az, 0, 0, 0);
                    ah = __builtin_amdgcn_mfma_f32_16x16x32_bf16(a, *(const bf16x8*)(wn + k), ah, 0, 0, 0);
                }
            }
            #pragma unroll
            for (int i = 0; i < 4; ++i) {
                l4[0][wave][lane][i] = ar[i];
                l4[1][wave][lane][i] = az[i];
                l4[2][wave][lane][i] = ai[i];
                l4[3][wave][lane][i] = ah[i];
            }
            __syncthreads();
            float sr = l4[0][0][sl][rg] + l4[0][1][sl][rg] + l4[0][2][sl][rg] + l4[0][3][sl][rg];
            float sz = l4[1][0][sl][rg] + l4[1][1][sl][rg] + l4[1][2][sl][rg] + l4[1][3][sl][rg];
            float si = l4[2][0][sl][rg] + l4[2][1][sl][rg] + l4[2][2][sl][rg] + l4[2][3][sl][rg];
            float sh = l4[3][0][sl][rg] + l4[3][1][sl][rg] + l4[3][2][sl][rg] + l4[3][3][sl][rg];
            int b = r0 + erow, m = m0 + ecol;
            float r = sigm(sr + p.dec_bih0[m] + p.dec_bhh0[m]);
            float z = sigm(sz + p.dec_bih0[M + m] + p.dec_bhh0[M + m]);
            float n = tanhf(si + p.dec_bih0[2 * M + m] + r * (sh + p.dec_bhh0[2 * M + m]));
            size_t hix = (size_t)b * M + m;
            float hv = (1.f - z) * n + z * p.h0f[hix];
            p.h0f[hix] = hv;
            unsigned hbits = f2bf(hv);
            unsigned up = __shfl_down(hbits, 1);
            if (!(tid & 1))
                cstoreu((unsigned*)(p.h0b + (size_t)pout * B * M + hix),
                        hbits | (up << 16));
        }
        gsync(p.bar, ph);
        // ---- stage 2: gru1 ----
        {
            int mt = blk & 63, bt = blk >> 6;
            int m0 = mt * 16, r0 = bt * 16;
            floatx4 ar = {0.f,0.f,0.f,0.f}, az = {0.f,0.f,0.f,0.f},
                    ai = {0.f,0.f,0.f,0.f}, ah = {0.f,0.f,0.f,0.f};
            const int Kq = M >> 2;
            {   // input side: x = h0 output
                const short* ap = p.h0b + (size_t)pout * B * M + (size_t)(r0 + lrow) * M + wave * Kq + ko8;
                const short* wr = p.wd_ih1 + (size_t)(m0 + lrow) * M + wave * Kq + ko8;
                const short* wz = wr + (size_t)M * M;
                const short* wn = wr + (size_t)2 * M * M;
                #pragma unroll
                for (int k = 0; k < Kq; k += 32) {
                    bf16x8 a = cload16(ap + k);
                    ar = __builtin_amdgcn_mfma_f32_16x16x32_bf16(a, *(const bf16x8*)(wr + k), ar, 0, 0, 0);
                    az = __builtin_amdgcn_mfma_f32_16x16x32_bf16(a, *(const bf16x8*)(wz + k), az, 0, 0, 0);
                    ai = __builtin_amdgcn_mfma_f32_16x16x32_bf16(a, *(const bf16x8*)(wn + k), ai, 0, 0, 0);
                }
            }
            {   // hidden side
                const short* ap = p.h1b + (size_t)pin * B * M + (size_t)(r0 + lrow) * M + wave * Kq + ko8;
                const short* wr = p.wd_hh1 + (size_t)(m0 + lrow) * M + wave * Kq + ko8;
                const short* wz = wr + (size_t)M * M;
                const short* wn = wr + (size_t)2 * M * M;
                #pragma unroll
                for (int k = 0; k < Kq; k += 32) {
                    bf16x8 a = cload16(ap + k);
                    ar = __builtin_amdgcn_mfma_f32_16x16x32_bf16(a, *(const bf16x8*)(wr + k), ar, 0, 0, 0);
                    az = __builtin_amdgcn_mfma_f32_16x16x32_bf16(a, *(const bf16x8*)(wz + k), az, 0, 0, 0);
                    ah = __builtin_amdgcn_mfma_f32_16x16x32_bf16(a, *(const bf16x8*)(wn + k), ah, 0, 0, 0);
                }
            }
            #pragma unroll
            for (int i = 0; i < 4; ++i) {
                l4[0][wave][lane][i] = ar[i];
                l4[1][wave][lane][i] = az[i];
                l4[2][wave][lane][i] = ai[i];
                l4[3][wave][lane][i] = ah[i];
            }
            __syncthreads();
            float sr = l4[0][0][sl][rg] + l4[0][1][sl][rg] + l4[0][2][sl][rg] + l4[0][3][sl][rg];
            float sz = l4[1][0][sl][rg] + l4[1][1][sl][rg] + l4[1][2][sl][rg] + l4[1][3][sl][rg];
            float si = l4[2][0][sl][rg] + l4[2][1][sl][rg] + l4[2][2][sl][rg] + l4[2][3][sl][rg];
            float sh = l4[3][0][sl][rg] + l4[3][1][sl][rg] + l4[3][2][sl][rg] + l4[3][3][sl][rg];
            int b = r0 + erow, m = m0 + ecol;
            float r = sigm(sr + p.dec_bih1[m] + p.dec_bhh1[m]);
            float z = sigm(sz + p.dec_bih1[M + m] + p.dec_bhh1[M + m]);
            float n = tanhf(si + p.dec_bih1[2 * M + m] + r * (sh + p.dec_bhh1[2 * M + m]));
            size_t hix = (size_t)b * M + m;
            float hv = (1.f - z) * n + z * p.h1f[hix];
            p.h1f[hix] = hv;
            unsigned hbits = f2bf(hv);
            unsigned up = __shfl_down(hbits, 1);
            if (!(tid & 1))
                cstoreu((unsigned*)(p.h1b + (size_t)pout * B * M + hix),
                        hbits | (up << 16));
        }
        gsync(p.bar, ph);
        // ---- stage 3: fc1 (512 tiles, 2 per block, K-split) ----
        {
            const short* Abase = p.h1b + (size_t)pout * B * M;
            const int Kq = M >> 2;
            #pragma unroll
            for (int half = 0; half < 2; ++half) {
                int T = blk + half * 256;
                int ct = T >> 2, rt = T & 3;
                const short* ap = Abase + (size_t)(rt * 16 + lrow) * M + wave * Kq + ko8;
                const short* wp = p.wfc1 + (size_t)(ct * 16 + lrow) * M + wave * Kq + ko8;
                floatx4 acc = {0.f, 0.f, 0.f, 0.f};
                #pragma unroll
                for (int k = 0; k < Kq; k += 32)
                    acc = __builtin_amdgcn_mfma_f32_16x16x32_bf16(
                        cload16(ap + k), *(const bf16x8*)(wp + k), acc, 0, 0, 0);
                #pragma unroll
                for (int i = 0; i < 4; ++i) l4[half][wave][lane][i] = acc[i];
            }
            __syncthreads();
            #pragma unroll
            for (int half = 0; half < 2; ++half) {
                int T = blk + half * 256;
                int ct = T >> 2, rt = T & 3;
                float s = l4[half][0][sl][rg] + l4[half][1][sl][rg] +
                          l4[half][2][sl][rg] + l4[half][3][sl][rg];
                cstoref(&p.zb[(size_t)(rt * 16 + erow) * LM + ct * 16 + ecol],
                        s + p.fc1_b[ct * 16 + ecol]);
            }
        }
        gsync(p.bar, ph);
        // ---- stage 4: LayerNorm + GELU (64 rows) ----
        if (blk < B) {
            const float* row = p.zb + (size_t)blk * LM;
            float v[8];
            float s = 0.f, ss = 0.f;
            #pragma unroll
            for (int it = 0; it < 4; ++it) {
                int i = tid * 2 + it * 512;
                float2 two = cload_f2(row + i);
                v[it * 2] = two.x; v[it * 2 + 1] = two.y;
                s += two.x + two.y; ss += two.x * two.x + two.y * two.y;
            }
            #pragma unroll
            for (int off = 32; off > 0; off >>= 1) {
                s += __shfl_down(s, off, 64);
                ss += __shfl_down(ss, off, 64);
            }
            if (lane == 0) { redA[wave] = s; redB[wave] = ss; }
            __syncthreads();
            float S = redA[0] + redA[1] + redA[2] + redA[3];
            float SS = redB[0] + redB[1] + redB[2] + redB[3];
            float mu = S * (1.f / LM);
            float var = SS * (1.f / LM) - mu * mu;
            float inv = rsqrtf(var + 1e-5f);
            #pragma unroll
            for (int it = 0; it < 4; ++it) {
                int i = tid * 2 + it * 512;
                float a0 = (v[it * 2] - mu) * inv * p.ln_g[i] + p.ln_b[i];
                float a1 = (v[it * 2 + 1] - mu) * inv * p.ln_g[i + 1] + p.ln_b[i + 1];
                float g0 = 0.5f * a0 * (1.f + erff(a0 * 0.70710678118654752f));
                float g1 = 0.5f * a1 * (1.f + erff(a1 * 0.70710678118654752f));
                unsigned packed = (unsigned)f2bf(g0) | ((unsigned)f2bf(g1) << 16);
                cstoreu((unsigned*)(p.zbb + (size_t)blk * LM + i), packed);
            }
        }
        gsync(p.bar, ph);
        // ---- stage 5: fc2 -> logits (128 tiles, K=2048 split) ----
        if (blk < 128) {
            int ct = blk >> 2, rt = blk & 3;
            const int Kq = LM >> 2;
            const short* ap = p.zbb + (size_t)(rt * 16 + lrow) * LM + wave * Kq + ko8;
            const short* wp = p.wfc2 + (size_t)(ct * 16 + lrow) * LM + wave * Kq + ko8;
            floatx4 acc = {0.f, 0.f, 0.f, 0.f};
            #pragma unroll 4
            for (int k = 0; k < Kq; k += 32)
                acc = __builtin_amdgcn_mfma_f32_16x16x32_bf16(
                    cload16(ap + k), *(const bf16x8*)(wp + k), acc, 0, 0, 0);
            #pragma unroll
            for (int i = 0; i < 4; ++i) l4[0][wave][lane][i] = acc[i];
            __syncthreads();
            float s = l4[0][0][sl][rg] + l4[0][1][sl][rg] +
                      l4[0][2][sl][rg] + l4[0][3][sl][rg];
            cstoref(&p.out[(size_t)(rt * 16 + erow) * (TDEC * O_DIM) +
                           (size_t)t * O_DIM + ct * 16 + ecol],
                    s + p.fc2_b[ct * 16 + ecol]);
        }
        gsync(p.bar, ph);
    }
}

extern "C" void kernel_launch(void* const* d_in, const int* in_sizes, int n_in,
                              void* d_out, int out_size, void* d_ws, size_t ws_size,
                              hipStream_t stream) {
    const float* X        = (const float*)d_in[0];
    const float* Y0       = (const float*)d_in[1];
    const float* enc_Wih0 = (const float*)d_in[2];
    const float* enc_Whh0 = (const float*)d_in[3];
    const float* enc_bih0 = (const float*)d_in[4];
    const float* enc_bhh0 = (const float*)d_in[5];
    const float* enc_Wih1 = (const float*)d_in[6];
    const float* enc_Whh1 = (const float*)d_in[7];
    const float* enc_bih1 = (const float*)d_in[8];
    const float* enc_bhh1 = (const float*)d_in[9];
    const float* dec_Wih0 = (const float*)d_in[10];
    const float* dec_Whh0 = (const float*)d_in[11];
    const float* dec_bih0 = (const float*)d_in[12];
    const float* dec_bhh0 = (const float*)d_in[13];
    const float* dec_Wih1 = (const float*)d_in[14];
    const float* dec_Whh1 = (const float*)d_in[15];
    const float* dec_bih1 = (const float*)d_in[16];
    const float* dec_bhh1 = (const float*)d_in[17];
    const float* fc1_w    = (const float*)d_in[18];
    const float* fc1_b    = (const float*)d_in[19];
    const float* ln_g     = (const float*)d_in[20];
    const float* ln_b     = (const float*)d_in[21];
    const float* fc2_w    = (const float*)d_in[22];
    const float* fc2_b    = (const float*)d_in[23];
    float* out = (float*)d_out;

    // ---- workspace carve-up ----
    char* wp_ = (char*)d_ws;
    auto carve = [&](size_t bytes) {
        void* r = wp_;
        wp_ += (bytes + 255) & ~(size_t)255;
        return r;
    };
    short* Xt    = (short*)carve((size_t)TIN * B * N_IN * 2);
    short* seqA  = (short*)carve((size_t)TIN * B * M * 2);
    float* gi_ch = (float*)carve((size_t)ECH * B * M3 * 4);     // 12 MB
    short* we_ih0 = (short*)carve((size_t)M3 * N_IN * 2);
    short* we_hh0 = (short*)carve((size_t)M3 * M * 2);
    short* we_ih1 = (short*)carve((size_t)M3 * M * 2);
    short* we_hh1 = (short*)carve((size_t)M3 * M * 2);
    short* wd_ih0 = (short*)carve((size_t)M3 * O_DIM * 2);
    short* wd_hh0 = (short*)carve((size_t)M3 * M * 2);
    short* wd_ih1 = (short*)carve((size_t)M3 * M * 2);
    short* wd_hh1 = (short*)carve((size_t)M3 * M * 2);
    short* wfc1   = (short*)carve((size_t)LM * M * 2);
    short* wfc2   = (short*)carve((size_t)O_DIM * LM * 2);
    float* h0f = (float*)carve((size_t)B * M * 4);
    float* h1f = (float*)carve((size_t)B * M * 4);
    short* h0b = (short*)carve((size_t)2 * B * M * 2);
    short* h1b = (short*)carve((size_t)2 * B * M * 2);
    short* yb  = (short*)carve((size_t)B * O_DIM * 2);
    float* zb  = (float*)carve((size_t)B * LM * 4);
    short* zbb = (short*)carve((size_t)B * LM * 2);
    unsigned* bar = (unsigned*)carve(256);

    auto cast = [&](const float* src, short* dst, int n) {
        cast_bf<<<(n + 255) / 256, 256, 0, stream>>>(src, dst, n);
    };
    cast(enc_Wih0, we_ih0, M3 * N_IN);
    cast(enc_Whh0, we_hh0, M3 * M);
    cast(enc_Wih1, we_ih1, M3 * M);
    cast(enc_Whh1, we_hh1, M3 * M);
    cast(dec_Wih0, wd_ih0, M3 * O_DIM);
    cast(dec_Whh0, wd_hh0, M3 * M);
    cast(dec_Wih1, wd_ih1, M3 * M);
    cast(dec_Whh1, wd_hh1, M3 * M);
    cast(fc1_w, wfc1, LM * M);
    cast(fc2_w, wfc2, O_DIM * LM);
    cast(Y0, yb, B * O_DIM);
    transpose_X_bf<<<(TIN * B * N_IN) / 256, 256, 0, stream>>>(X, Xt);

    hipMemsetAsync(h0f, 0, (size_t)B * M * 4, stream);
    hipMemsetAsync(h1f, 0, (size_t)B * M * 4, stream);
    hipMemsetAsync(h0b, 0, (size_t)B * M * 2, stream);   // parity-0
    hipMemsetAsync(h1b, 0, (size_t)B * M * 2, stream);
    hipMemsetAsync(bar, 0, 256, stream);

    Params hp;
    hp.Xt = Xt; hp.seqA = seqA; hp.gi = gi_ch;
    hp.we_ih0 = we_ih0; hp.we_hh0 = we_hh0; hp.we_ih1 = we_ih1; hp.we_hh1 = we_hh1;
    hp.wd_ih0 = wd_ih0; hp.wd_hh0 = wd_hh0; hp.wd_ih1 = wd_ih1; hp.wd_hh1 = wd_hh1;
    hp.wfc1 = wfc1; hp.wfc2 = wfc2;
    hp.enc_bih0 = enc_bih0; hp.enc_bhh0 = enc_bhh0;
    hp.enc_bih1 = enc_bih1; hp.enc_bhh1 = enc_bhh1;
    hp.dec_bih0 = dec_bih0; hp.dec_bhh0 = dec_bhh0;
    hp.dec_bih1 = dec_bih1; hp.dec_bhh1 = dec_bhh1;
    hp.fc1_b = fc1_b; hp.ln_g = ln_g; hp.ln_b = ln_b; hp.fc2_b = fc2_b;
    hp.h0f = h0f; hp.h1f = h1f; hp.h0b = h0b; hp.h1b = h1b;
    hp.yb = yb; hp.zb = zb; hp.zbb = zbb; hp.out = out;
    hp.bar = bar;

    mega<<<dim3(NBLK), dim3(256), 0, stream>>>(hp);
}

// Round 8
// 7863.983 us; speedup vs baseline: 2.6564x; 1.0808x over previous
//
#include <hip/hip_runtime.h>
#include <math.h>

#define B 64
#define TIN 128
#define N_IN 256
#define M 1024
#define O_DIM 512
#define LM 2048
#define TDEC 64
#define M3 3072
#define ECH 16   // encoder gi timestep chunk
#define NBLK 256

typedef short bf16x8 __attribute__((ext_vector_type(8)));
typedef float floatx4 __attribute__((ext_vector_type(4)));
typedef unsigned long long u64t;

__device__ __forceinline__ unsigned short f2bf(float f) {
    unsigned int u = __float_as_uint(f);
    u += 0x7FFFu + ((u >> 16) & 1u);      // round-to-nearest-even
    return (unsigned short)(u >> 16);
}
__device__ __forceinline__ float sigm(float x) { return 1.f / (1.f + expf(-x)); }

// ---- coherent (agent-scope, L2-bypassing) access helpers -------------------
__device__ __forceinline__ u64t cload_u64(const void* p) {
    return __hip_atomic_load((const u64t*)p, __ATOMIC_RELAXED, __HIP_MEMORY_SCOPE_AGENT);
}
__device__ __forceinline__ float2 cload_f2(const float* p) {
    union { u64t u; float2 f; } c; c.u = cload_u64(p); return c.f;
}
__device__ __forceinline__ float cloadf(const float* p) {
    union { unsigned u; float f; } c;
    c.u = __hip_atomic_load((const unsigned*)p, __ATOMIC_RELAXED, __HIP_MEMORY_SCOPE_AGENT);
    return c.f;
}
__device__ __forceinline__ void cstoref(float* p, float v) {
    union { unsigned u; float f; } c; c.f = v;
    __hip_atomic_store((unsigned*)p, c.u, __ATOMIC_RELAXED, __HIP_MEMORY_SCOPE_AGENT);
}
__device__ __forceinline__ void cstoreu(unsigned* p, unsigned v) {
    __hip_atomic_store(p, v, __ATOMIC_RELAXED, __HIP_MEMORY_SCOPE_AGENT);
}
__device__ __forceinline__ bf16x8 cload16(const short* p) {
    union { u64t u[2]; bf16x8 v; } c;
    c.u[0] = cload_u64(p);
    c.u[1] = cload_u64(p + 4);
    return c.v;
}

// grid barrier: striped arrive (16 lines) + master aggregate + broadcast flag.
// bar layout (unsigned words): stripes at [i*16] i<16; flag at [255].
__device__ __forceinline__ void gsync(unsigned* bar, unsigned& phase, int blk) {
    __syncthreads();                    // drains all waves' vmcnt (HIP semantics)
    if (threadIdx.x == 0) {
        phase += 1;
        __hip_atomic_fetch_add(&bar[(blk & 15) * 16], 1u,
                               __ATOMIC_RELAXED, __HIP_MEMORY_SCOPE_AGENT);
        if (blk == 0) {
            for (;;) {
                unsigned sum = 0;
                #pragma unroll
                for (int i = 0; i < 16; ++i)
                    sum += __hip_atomic_load(&bar[i * 16], __ATOMIC_RELAXED,
                                             __HIP_MEMORY_SCOPE_AGENT);
                if (sum >= phase * NBLK) break;
                __builtin_amdgcn_s_sleep(1);
            }
            __hip_atomic_store(&bar[255], phase, __ATOMIC_RELAXED,
                               __HIP_MEMORY_SCOPE_AGENT);
        } else {
            while (__hip_atomic_load(&bar[255], __ATOMIC_RELAXED,
                                     __HIP_MEMORY_SCOPE_AGENT) < phase)
                __builtin_amdgcn_s_sleep(1);
        }
    }
    __syncthreads();
}

// ---------------------------------------------------------------------------
// pre-kernels: casts / transpose
// ---------------------------------------------------------------------------
__global__ __launch_bounds__(256) void cast_bf(const float* __restrict__ in,
                                               short* __restrict__ out, int n) {
    int i = blockIdx.x * 256 + threadIdx.x;
    if (i < n) out[i] = (short)f2bf(in[i]);
}

__global__ __launch_bounds__(256) void transpose_X_bf(const float* __restrict__ X,
                                                      short* __restrict__ Xt) {
    int idx = blockIdx.x * 256 + threadIdx.x;   // t*(B*N) + b*N + n
    int n = idx & (N_IN - 1);
    int b = (idx >> 8) & (B - 1);
    int t = idx >> 14;
    Xt[idx] = (short)f2bf(X[(b * TIN + t) * N_IN + n]);
}

// ---------------------------------------------------------------------------
// megakernel params
// ---------------------------------------------------------------------------
struct Params {
    const short *Xt;
    short *seqA;
    float *gi;                                   // ECH*B*M3 fp32 chunk buffer
    const short *we_ih0, *we_hh0, *we_ih1, *we_hh1;
    const short *wd_ih0, *wd_hh0, *wd_ih1, *wd_hh1, *wfc1, *wfc2;
    const float *enc_bih0, *enc_bhh0, *enc_bih1, *enc_bhh1;
    const float *dec_bih0, *dec_bhh0, *dec_bih1, *dec_bhh1;
    const float *fc1_b, *ln_g, *ln_b, *fc2_b;
    float *h0f, *h1f;
    short *h0b, *h1b;                            // 2x B*M ping-pong each
    const short *yb;                             // Y0 bf16
    float *zb;                                   // B*LM fp32
    short *zbb;                                  // B*LM bf16
    float *out;                                  // d_out logits
    unsigned *bar;                               // grid barrier region
};

// ---------------------------------------------------------------------------
// One persistent kernel: full encoder + decoder. 256 blocks x 256 threads.
// ---------------------------------------------------------------------------
__global__ __launch_bounds__(256, 1) void mega(Params p) {
    const int blk  = blockIdx.x;
    const int tid  = threadIdx.x;
    const int wave = tid >> 6;
    const int lane = tid & 63;
    const int lrow = lane & 15;
    const int ko8  = (lane >> 4) * 8;
    const int wid  = blk * 4 + wave;            // 0..1023
    // epilogue / reduce thread mapping
    const int erow = tid >> 4, ecol = tid & 15;
    const int sl = (erow >> 2) * 16 + ecol, rg = erow & 3;
    unsigned ph = 0;

    __shared__ float l4[4][4][64][4];           // [gate][wave][lane][i]
    __shared__ short ylds[16][520];             // +8 pad: 2-way banks only
    __shared__ float redA[4], redB[4];

    // ================= encoder =================
    #pragma unroll 1
    for (int layer = 0; layer < 2; ++layer) {
        const bool lay1 = (layer == 1);
        const short* Wih = lay1 ? p.we_ih1 : p.we_ih0;
        const short* Whh = lay1 ? p.we_hh1 : p.we_hh0;
        const float* bih = lay1 ? p.enc_bih1 : p.enc_bih0;
        const float* bhh = lay1 ? p.enc_bhh1 : p.enc_bhh0;
        const short* inseq = lay1 ? p.seqA : p.Xt;
        const int Kin = lay1 ? M : N_IN;
        float* hf = lay1 ? p.h1f : p.h0f;
        short* hb = lay1 ? p.h1b : p.h0b;
        #pragma unroll 1
        for (int c = 0; c < TIN / ECH; ++c) {
            // ---- gi GEMM for ECH steps: rows=ECH*B=1024, cols=3072 ----
            // Each wave owns ONE row-tile (rt = wid&63) and 12 col-tiles
            // (ct = (wid>>6) + 16j) -> A loaded once per k-chunk, reused x12.
            {
                const short* Abase = inseq + (size_t)c * ECH * B * Kin;
                const int rt = wid & 63, ctb = wid >> 6;
                const int r0 = rt * 16;
                const short* ap = Abase + (size_t)(r0 + lrow) * Kin + ko8;
                floatx4 acc[12];
                #pragma unroll
                for (int j = 0; j < 12; ++j) acc[j] = (floatx4){0.f, 0.f, 0.f, 0.f};
                #pragma unroll 1
                for (int kc = 0; kc < Kin; kc += 256) {
                    bf16x8 aReg[8];
                    #pragma unroll
                    for (int i = 0; i < 8; ++i)
                        aReg[i] = lay1 ? cload16(ap + kc + i * 32)
                                       : *(const bf16x8*)(ap + kc + i * 32);
                    #pragma unroll
                    for (int j = 0; j < 12; ++j) {
                        const int c0 = (ctb + 16 * j) * 16;
                        const short* wp = Wih + (size_t)(c0 + lrow) * Kin + kc + ko8;
                        #pragma unroll
                        for (int i = 0; i < 8; ++i)
                            acc[j] = __builtin_amdgcn_mfma_f32_16x16x32_bf16(
                                aReg[i], *(const bf16x8*)(wp + i * 32), acc[j], 0, 0, 0);
                    }
                }
                const int rbase = r0 + (lane >> 4) * 4;
                #pragma unroll
                for (int j = 0; j < 12; ++j) {
                    int col = (ctb + 16 * j) * 16 + lrow;
                    float bv = bih[col];
                    #pragma unroll
                    for (int i = 0; i < 4; ++i)
                        cstoref(&p.gi[(size_t)(rbase + i) * M3 + col], acc[j][i] + bv);
                }
            }
            gsync(p.bar, ph, blk);
            // ---- ECH sequential GRU steps, one 16x16 tile per block ----
            #pragma unroll 1
            for (int tt = 0; tt < ECH; ++tt) {
                int t = c * ECH + tt;
                int pin = t & 1, pout = pin ^ 1;
                const short* hin = hb + (size_t)pin * B * M;
                short* hout = hb + (size_t)pout * B * M;
                short* so = (layer == 0) ? (p.seqA + (size_t)t * B * M) : nullptr;
                const float* gi = p.gi + (size_t)tt * B * M3;
                int mt = blk & 63, bt = blk >> 6;
                int m0 = mt * 16, r0 = bt * 16;
                const int Kq = M >> 2;
                const short* ap = hin + (size_t)(r0 + lrow) * M + wave * Kq + ko8;
                const short* wr = Whh + (size_t)(m0 + lrow) * M + wave * Kq + ko8;
                const short* wz = wr + (size_t)M * M;
                const short* wn = wr + (size_t)2 * M * M;
                bf16x8 aReg[8];
                #pragma unroll
                for (int k = 0; k < 8; ++k) aReg[k] = cload16(ap + k * 32);
                floatx4 ar = {0.f,0.f,0.f,0.f}, az = {0.f,0.f,0.f,0.f},
                        ah = {0.f,0.f,0.f,0.f};
                #pragma unroll
                for (int k = 0; k < 8; ++k) {
                    ar = __builtin_amdgcn_mfma_f32_16x16x32_bf16(aReg[k], *(const bf16x8*)(wr + k * 32), ar, 0, 0, 0);
                    az = __builtin_amdgcn_mfma_f32_16x16x32_bf16(aReg[k], *(const bf16x8*)(wz + k * 32), az, 0, 0, 0);
                    ah = __builtin_amdgcn_mfma_f32_16x16x32_bf16(aReg[k], *(const bf16x8*)(wn + k * 32), ah, 0, 0, 0);
                }
                #pragma unroll
                for (int i = 0; i < 4; ++i) {
                    l4[0][wave][lane][i] = ar[i];
                    l4[1][wave][lane][i] = az[i];
                    l4[2][wave][lane][i] = ah[i];
                }
                __syncthreads();
                float sr = l4[0][0][sl][rg] + l4[0][1][sl][rg] + l4[0][2][sl][rg] + l4[0][3][sl][rg];
                float sz = l4[1][0][sl][rg] + l4[1][1][sl][rg] + l4[1][2][sl][rg] + l4[1][3][sl][rg];
                float sh = l4[2][0][sl][rg] + l4[2][1][sl][rg] + l4[2][2][sl][rg] + l4[2][3][sl][rg];
                int b = r0 + erow, m = m0 + ecol;
                const float* gir = gi + (size_t)b * M3;
                float r = sigm(cloadf(gir + m) + sr + bhh[m]);
                float z = sigm(cloadf(gir + M + m) + sz + bhh[M + m]);
                float n = tanhf(cloadf(gir + 2 * M + m) + r * (sh + bhh[2 * M + m]));
                size_t hix = (size_t)b * M + m;
                float hv = (1.f - z) * n + z * hf[hix];
                hf[hix] = hv;
                unsigned hbits = f2bf(hv);
                unsigned up = __shfl_down(hbits, 1);
                if (!(tid & 1)) {
                    unsigned packed = hbits | (up << 16);
                    cstoreu((unsigned*)(hout + hix), packed);
                    if (so) cstoreu((unsigned*)(so + hix), packed);
                }
                gsync(p.bar, ph, blk);
            }
        }
    }

    // ================= decoder =================
    #pragma unroll 1
    for (int t = 0; t < TDEC; ++t) {
        int pin = t & 1, pout = pin ^ 1;
        // ---- stage 1: gru0 (inline softmax of prev logits -> ylds) ----
        {
            int mt = blk & 63, bt = blk >> 6;
            int m0 = mt * 16, r0 = bt * 16;
            if (t == 0) {
                for (int idx = tid; idx < 16 * O_DIM; idx += 256) {
                    int rr = idx >> 9, cc = idx & 511;
                    ylds[rr][cc] = p.yb[(size_t)(r0 + rr) * O_DIM + cc];
                }
            } else {
                const float* lbase = p.out + (size_t)(t - 1) * O_DIM;
                #pragma unroll
                for (int q = 0; q < 4; ++q) {
                    int rr = wave * 4 + q;
                    const float* rowp = lbase + (size_t)(r0 + rr) * (TDEC * O_DIM);
                    float v[8];
                    float mx = -1e30f;
                    #pragma unroll
                    for (int j2 = 0; j2 < 4; ++j2) {
                        float2 two = cload_f2(rowp + lane * 8 + j2 * 2);
                        v[j2 * 2] = two.x; v[j2 * 2 + 1] = two.y;
                        mx = fmaxf(mx, fmaxf(two.x, two.y));
                    }
                    #pragma unroll
                    for (int off = 32; off > 0; off >>= 1) mx = fmaxf(mx, __shfl_xor(mx, off));
                    float s = 0.f;
                    #pragma unroll
                    for (int j = 0; j < 8; ++j) { v[j] = expf(v[j] - mx); s += v[j]; }
                    #pragma unroll
                    for (int off = 32; off > 0; off >>= 1) s += __shfl_xor(s, off);
                    float inv = 1.f / s;
                    #pragma unroll
                    for (int j = 0; j < 8; ++j) ylds[rr][lane * 8 + j] = (short)f2bf(v[j] * inv);
                }
            }
            __syncthreads();
            // hidden-side A prefetch (coherent)
            const int Kq = M >> 2;
            const short* aph = p.h0b + (size_t)pin * B * M + (size_t)(r0 + lrow) * M + wave * Kq + ko8;
            bf16x8 aHid[8];
            #pragma unroll
            for (int k = 0; k < 8; ++k) aHid[k] = cload16(aph + k * 32);
            floatx4 ar = {0.f,0.f,0.f,0.f}, az = {0.f,0.f,0.f,0.f},
                    ai = {0.f,0.f,0.f,0.f}, ah = {0.f,0.f,0.f,0.f};
            {   // input side from LDS, K=512
                const int Kqi = O_DIM >> 2;
                const short* aL = &ylds[lrow][wave * Kqi + ko8];
                const short* wr = p.wd_ih0 + (size_t)(m0 + lrow) * O_DIM + wave * Kqi + ko8;
                const short* wz = wr + (size_t)M * O_DIM;
                const short* wn = wr + (size_t)2 * M * O_DIM;
                #pragma unroll
                for (int k = 0; k < 4; ++k) {
                    bf16x8 a = *(const bf16x8*)(aL + k * 32);
                    ar = __builtin_amdgcn_mfma_f32_16x16x32_bf16(a, *(const bf16x8*)(wr + k * 32), ar, 0, 0, 0);
                    az = __builtin_amdgcn_mfma_f32_16x16x32_bf16(a, *(const bf16x8*)(wz + k * 32), az, 0, 0, 0);
                    ai = __builtin_amdgcn_mfma_f32_16x16x32_bf16(a, *(const bf16x8*)(wn + k * 32), ai, 0, 0, 0);
                }
            }
            {   // hidden side, K=1024 (prefetched)
                const short* wr = p.wd_hh0 + (size_t)(m0 + lrow) * M + wave * Kq + ko8;
                const short* wz = wr + (size_t)M * M;
                const short* wn = wr + (size_t)2 * M * M;
                #pragma unroll
                for (int k = 0; k < 8; ++k) {
                    ar = __builtin_amdgcn_mfma_f32_16x16x32_bf16(aHid[k], *(const bf16x8*)(wr + k * 32), ar, 0, 0, 0);
                    az = __builtin_amdgcn_mfma_f32_16x16x32_bf16(aHid[k], *(const bf16x8*)(wz + k * 32), az, 0, 0, 0);
                    ah = __builtin_amdgcn_mfma_f32_16x16x32_bf16(aHid[k], *(const bf16x8*)(wn + k * 32), ah, 0, 0, 0);
                }
            }
            #pragma unroll
            for (int i = 0; i < 4; ++i) {
                l4[0][wave][lane][i] = ar[i];
                l4[1][wave][lane][i] = az[i];
                l4[2][wave][lane][i] = ai[i];
                l4[3][wave][lane][i] = ah[i];
            }
            __syncthreads();
            float sr = l4[0][0][sl][rg] + l4[0][1][sl][rg] + l4[0][2][sl][rg] + l4[0][3][sl][rg];
            float sz = l4[1][0][sl][rg] + l4[1][1][sl][rg] + l4[1][2][sl][rg] + l4[1][3][sl][rg];
            float si = l4[2][0][sl][rg] + l4[2][1][sl][rg] + l4[2][2][sl][rg] + l4[2][3][sl][rg];
            float sh = l4[3][0][sl][rg] + l4[3][1][sl][rg] + l4[3][2][sl][rg] + l4[3][3][sl][rg];
            int b = r0 + erow, m = m0 + ecol;
            float r = sigm(sr + p.dec_bih0[m] + p.dec_bhh0[m]);
            float z = sigm(sz + p.dec_bih0[M + m] + p.dec_bhh0[M + m]);
            float n = tanhf(si + p.dec_bih0[2 * M + m] + r * (sh + p.dec_bhh0[2 * M + m]));
            size_t hix = (size_t)b * M + m;
            float hv = (1.f - z) * n + z * p.h0f[hix];
            p.h0f[hix] = hv;
            unsigned hbits = f2bf(hv);
            unsigned up = __shfl_down(hbits, 1);
            if (!(tid & 1))
                cstoreu((unsigned*)(p.h0b + (size_t)pout * B * M + hix),
                        hbits | (up << 16));
        }
        gsync(p.bar, ph, blk);
        // ---- stage 2: gru1 ----
        {
            int mt = blk & 63, bt = blk >> 6;
            int m0 = mt * 16, r0 = bt * 16;
            const int Kq = M >> 2;
            const short* api = p.h0b + (size_t)pout * B * M + (size_t)(r0 + lrow) * M + wave * Kq + ko8;
            const short* aph = p.h1b + (size_t)pin * B * M + (size_t)(r0 + lrow) * M + wave * Kq + ko8;
            bf16x8 aIn[8], aHid[8];
            #pragma unroll
            for (int k = 0; k < 8; ++k) aIn[k] = cload16(api + k * 32);
            #pragma unroll
            for (int k = 0; k < 8; ++k) aHid[k] = cload16(aph + k * 32);
            floatx4 ar = {0.f,0.f,0.f,0.f}, az = {0.f,0.f,0.f,0.f},
                    ai = {0.f,0.f,0.f,0.f}, ah = {0.f,0.f,0.f,0.f};
            {   // input side: x = h0 output
                const short* wr = p.wd_ih1 + (size_t)(m0 + lrow) * M + wave * Kq + ko8;
                const short* wz = wr + (size_t)M * M;
                const short* wn = wr + (size_t)2 * M * M;
                #pragma unroll
                for (int k = 0; k < 8; ++k) {
                    ar = __builtin_amdgcn_mfma_f32_16x16x32_bf16(aIn[k], *(const bf16x8*)(wr + k * 32), ar, 0, 0, 0);
                    az = __builtin_amdgcn_mfma_f32_16x16x32_bf16(aIn[k], *(const bf16x8*)(wz + k * 32), az, 0, 0, 0);
                    ai = __builtin_amdgcn_mfma_f32_16x16x32_bf16(aIn[k], *(const bf16x8*)(wn + k * 32), ai, 0, 0, 0);
                }
            }
            {   // hidden side
                const short* wr = p.wd_hh1 + (size_t)(m0 + lrow) * M + wave * Kq + ko8;
                const short* wz = wr + (size_t)M * M;
                const short* wn = wr + (size_t)2 * M * M;
                #pragma unroll
                for (int k = 0; k < 8; ++k) {
                    ar = __builtin_amdgcn_mfma_f32_16x16x32_bf16(aHid[k], *(const bf16x8*)(wr + k * 32), ar, 0, 0, 0);
                    az = __builtin_amdgcn_mfma_f32_16x16x32_bf16(aHid[k], *(const bf16x8*)(wz + k * 32), az, 0, 0, 0);
                    ah = __builtin_amdgcn_mfma_f32_16x16x32_bf16(aHid[k], *(const bf16x8*)(wn + k * 32), ah, 0, 0, 0);
                }
            }
            #pragma unroll
            for (int i = 0; i < 4; ++i) {
                l4[0][wave][lane][i] = ar[i];
                l4[1][wave][lane][i] = az[i];
                l4[2][wave][lane][i] = ai[i];
                l4[3][wave][lane][i] = ah[i];
            }
            __syncthreads();
            float sr = l4[0][0][sl][rg] + l4[0][1][sl][rg] + l4[0][2][sl][rg] + l4[0][3][sl][rg];
            float sz = l4[1][0][sl][rg] + l4[1][1][sl][rg] + l4[1][2][sl][rg] + l4[1][3][sl][rg];
            float si = l4[2][0][sl][rg] + l4[2][1][sl][rg] + l4[2][2][sl][rg] + l4[2][3][sl][rg];
            float sh = l4[3][0][sl][rg] + l4[3][1][sl][rg] + l4[3][2][sl][rg] + l4[3][3][sl][rg];
            int b = r0 + erow, m = m0 + ecol;
            float r = sigm(sr + p.dec_bih1[m] + p.dec_bhh1[m]);
            float z = sigm(sz + p.dec_bih1[M + m] + p.dec_bhh1[M + m]);
            float n = tanhf(si + p.dec_bih1[2 * M + m] + r * (sh + p.dec_bhh1[2 * M + m]));
            size_t hix = (size_t)b * M + m;
            float hv = (1.f - z) * n + z * p.h1f[hix];
            p.h1f[hix] = hv;
            unsigned hbits = f2bf(hv);
            unsigned up = __shfl_down(hbits, 1);
            if (!(tid & 1))
                cstoreu((unsigned*)(p.h1b + (size_t)pout * B * M + hix),
                        hbits | (up << 16));
        }
        gsync(p.bar, ph, blk);
        // ---- stage 3: fc1 (512 tiles, 2 per block, K-split; A shared) ----
        {
            const short* Abase = p.h1b + (size_t)pout * B * M;
            const int Kq = M >> 2;
            const int rt = blk & 3;     // same for both halves
            const short* ap = Abase + (size_t)(rt * 16 + lrow) * M + wave * Kq + ko8;
            bf16x8 aReg[8];
            #pragma unroll
            for (int k = 0; k < 8; ++k) aReg[k] = cload16(ap + k * 32);
            #pragma unroll
            for (int half = 0; half < 2; ++half) {
                int T = blk + half * 256;
                int ct = T >> 2;
                const short* wp = p.wfc1 + (size_t)(ct * 16 + lrow) * M + wave * Kq + ko8;
                floatx4 acc = {0.f, 0.f, 0.f, 0.f};
                #pragma unroll
                for (int k = 0; k < 8; ++k)
                    acc = __builtin_amdgcn_mfma_f32_16x16x32_bf16(
                        aReg[k], *(const bf16x8*)(wp + k * 32), acc, 0, 0, 0);
                #pragma unroll
                for (int i = 0; i < 4; ++i) l4[half][wave][lane][i] = acc[i];
            }
            __syncthreads();
            #pragma unroll
            for (int half = 0; half < 2; ++half) {
                int T = blk + half * 256;
                int ct = T >> 2;
                float s = l4[half][0][sl][rg] + l4[half][1][sl][rg] +
                          l4[half][2][sl][rg] + l4[half][3][sl][rg];
                cstoref(&p.zb[(size_t)(rt * 16 + erow) * LM + ct * 16 + ecol],
                        s + p.fc1_b[ct * 16 + ecol]);
            }
        }
        gsync(p.bar, ph, blk);
        // ---- stage 4: LayerNorm + GELU (64 rows) ----
        if (blk < B) {
            const float* row = p.zb + (size_t)blk * LM;
            float v[8];
            float s = 0.f, ss = 0.f;
            #pragma unroll
            for (int it = 0; it < 4; ++it) {
                int i = tid * 2 + it * 512;
                float2 two = cload_f2(row + i);
                v[it * 2] = two.x; v[it * 2 + 1] = two.y;
                s += two.x + two.y; ss += two.x * two.x + two.y * two.y;
            }
            #pragma unroll
            for (int off = 32; off > 0; off >>= 1) {
                s += __shfl_down(s, off, 64);
                ss += __shfl_down(ss, off, 64);
            }
            if (lane == 0) { redA[wave] = s; redB[wave] = ss; }
            __syncthreads();
            float S = redA[0] + redA[1] + redA[2] + redA[3];
            float SS = redB[0] + redB[1] + redB[2] + redB[3];
            float mu = S * (1.f / LM);
            float var = SS * (1.f / LM) - mu * mu;
            float inv = rsqrtf(var + 1e-5f);
            #pragma unroll
            for (int it = 0; it < 4; ++it) {
                int i = tid * 2 + it * 512;
                float a0 = (v[it * 2] - mu) * inv * p.ln_g[i] + p.ln_b[i];
                float a1 = (v[it * 2 + 1] - mu) * inv * p.ln_g[i + 1] + p.ln_b[i + 1];
                float g0 = 0.5f * a0 * (1.f + erff(a0 * 0.70710678118654752f));
                float g1 = 0.5f * a1 * (1.f + erff(a1 * 0.70710678118654752f));
                unsigned packed = (unsigned)f2bf(g0) | ((unsigned)f2bf(g1) << 16);
                cstoreu((unsigned*)(p.zbb + (size_t)blk * LM + i), packed);
            }
        }
        gsync(p.bar, ph, blk);
        // ---- stage 5: fc2 -> logits (128 tiles, K=2048 split) ----
        if (blk < 128) {
            int ct = blk >> 2, rt = blk & 3;
            const int Kq = LM >> 2;
            const short* ap = p.zbb + (size_t)(rt * 16 + lrow) * LM + wave * Kq + ko8;
            const short* wp = p.wfc2 + (size_t)(ct * 16 + lrow) * LM + wave * Kq + ko8;
            bf16x8 aReg[16];
            #pragma unroll
            for (int k = 0; k < 16; ++k) aReg[k] = cload16(ap + k * 32);
            floatx4 acc = {0.f, 0.f, 0.f, 0.f};
            #pragma unroll
            for (int k = 0; k < 16; ++k)
                acc = __builtin_amdgcn_mfma_f32_16x16x32_bf16(
                    aReg[k], *(const bf16x8*)(wp + k * 32), acc, 0, 0, 0);
            #pragma unroll
            for (int i = 0; i < 4; ++i) l4[0][wave][lane][i] = acc[i];
            __syncthreads();
            float s = l4[0][0][sl][rg] + l4[0][1][sl][rg] +
                      l4[0][2][sl][rg] + l4[0][3][sl][rg];
            cstoref(&p.out[(size_t)(rt * 16 + erow) * (TDEC * O_DIM) +
                           (size_t)t * O_DIM + ct * 16 + ecol],
                    s + p.fc2_b[ct * 16 + ecol]);
        }
        gsync(p.bar, ph, blk);
    }
}

extern "C" void kernel_launch(void* const* d_in, const int* in_sizes, int n_in,
                              void* d_out, int out_size, void* d_ws, size_t ws_size,
                              hipStream_t stream) {
    const float* X        = (const float*)d_in[0];
    const float* Y0       = (const float*)d_in[1];
    const float* enc_Wih0 = (const float*)d_in[2];
    const float* enc_Whh0 = (const float*)d_in[3];
    const float* enc_bih0 = (const float*)d_in[4];
    const float* enc_bhh0 = (const float*)d_in[5];
    const float* enc_Wih1 = (const float*)d_in[6];
    const float* enc_Whh1 = (const float*)d_in[7];
    const float* enc_bih1 = (const float*)d_in[8];
    const float* enc_bhh1 = (const float*)d_in[9];
    const float* dec_Wih0 = (const float*)d_in[10];
    const float* dec_Whh0 = (const float*)d_in[11];
    const float* dec_bih0 = (const float*)d_in[12];
    const float* dec_bhh0 = (const float*)d_in[13];
    const float* dec_Wih1 = (const float*)d_in[14];
    const float* dec_Whh1 = (const float*)d_in[15];
    const float* dec_bih1 = (const float*)d_in[16];
    const float* dec_bhh1 = (const float*)d_in[17];
    const float* fc1_w    = (const float*)d_in[18];
    const float* fc1_b    = (const float*)d_in[19];
    const float* ln_g     = (const float*)d_in[20];
    const float* ln_b     = (const float*)d_in[21];
    const float* fc2_w    = (const float*)d_in[22];
    const float* fc2_b    = (const float*)d_in[23];
    float* out = (float*)d_out;

    // ---- workspace carve-up ----
    char* wp_ = (char*)d_ws;
    auto carve = [&](size_t bytes) {
        void* r = wp_;
        wp_ += (bytes + 255) & ~(size_t)255;
        return r;
    };
    short* Xt    = (short*)carve((size_t)TIN * B * N_IN * 2);
    short* seqA  = (short*)carve((size_t)TIN * B * M * 2);
    float* gi_ch = (float*)carve((size_t)ECH * B * M3 * 4);     // 12 MB
    short* we_ih0 = (short*)carve((size_t)M3 * N_IN * 2);
    short* we_hh0 = (short*)carve((size_t)M3 * M * 2);
    short* we_ih1 = (short*)carve((size_t)M3 * M * 2);
    short* we_hh1 = (short*)carve((size_t)M3 * M * 2);
    short* wd_ih0 = (short*)carve((size_t)M3 * O_DIM * 2);
    short* wd_hh0 = (short*)carve((size_t)M3 * M * 2);
    short* wd_ih1 = (short*)carve((size_t)M3 * M * 2);
    short* wd_hh1 = (short*)carve((size_t)M3 * M * 2);
    short* wfc1   = (short*)carve((size_t)LM * M * 2);
    short* wfc2   = (short*)carve((size_t)O_DIM * LM * 2);
    float* h0f = (float*)carve((size_t)B * M * 4);
    float* h1f = (float*)carve((size_t)B * M * 4);
    short* h0b = (short*)carve((size_t)2 * B * M * 2);
    short* h1b = (short*)carve((size_t)2 * B * M * 2);
    short* yb  = (short*)carve((size_t)B * O_DIM * 2);
    float* zb  = (float*)carve((size_t)B * LM * 4);
    short* zbb = (short*)carve((size_t)B * LM * 2);
    unsigned* bar = (unsigned*)carve(1024);

    auto cast = [&](const float* src, short* dst, int n) {
        cast_bf<<<(n + 255) / 256, 256, 0, stream>>>(src, dst, n);
    };
    cast(enc_Wih0, we_ih0, M3 * N_IN);
    cast(enc_Whh0, we_hh0, M3 * M);
    cast(enc_Wih1, we_ih1, M3 * M);
    cast(enc_Whh1, we_hh1, M3 * M);
    cast(dec_Wih0, wd_ih0, M3 * O_DIM);
    cast(dec_Whh0, wd_hh0, M3 * M);
    cast(dec_Wih1, wd_ih1, M3 * M);
    cast(dec_Whh1, wd_hh1, M3 * M);
    cast(fc1_w, wfc1, LM * M);
    cast(fc2_w, wfc2, O_DIM * LM);
    cast(Y0, yb, B * O_DIM);
    transpose_X_bf<<<(TIN * B * N_IN) / 256, 256, 0, stream>>>(X, Xt);

    hipMemsetAsync(h0f, 0, (size_t)B * M * 4, stream);
    hipMemsetAsync(h1f, 0, (size_t)B * M * 4, stream);
    hipMemsetAsync(h0b, 0, (size_t)B * M * 2, stream);   // parity-0
    hipMemsetAsync(h1b, 0, (size_t)B * M * 2, stream);
    hipMemsetAsync(bar, 0, 1024, stream);

    Params hp;
    hp.Xt = Xt; hp.seqA = seqA; hp.gi = gi_ch;
    hp.we_ih0 = we_ih0; hp.we_hh0 = we_hh0; hp.we_ih1 = we_ih1; hp.we_hh1 = we_hh1;
    hp.wd_ih0 = wd_ih0; hp.wd_hh0 = wd_hh0; hp.wd_ih1 = wd_ih1; hp.wd_hh1 = wd_hh1;
    hp.wfc1 = wfc1; hp.wfc2 = wfc2;
    hp.enc_bih0 = enc_bih0; hp.enc_bhh0 = enc_bhh0;
    hp.enc_bih1 = enc_bih1; hp.enc_bhh1 = enc_bhh1;
    hp.dec_bih0 = dec_bih0; hp.dec_bhh0 = dec_bhh0;
    hp.dec_bih1 = dec_bih1; hp.dec_bhh1 = dec_bhh1;
    hp.fc1_b = fc1_b; hp.ln_g = ln_g; hp.ln_b = ln_b; hp.fc2_b = fc2_b;
    hp.h0f = h0f; hp.h1f = h1f; hp.h0b = h0b; hp.h1b = h1b;
    hp.yb = yb; hp.zb = zb; hp.zbb = zbb; hp.out = out;
    hp.bar = bar;

    mega<<<dim3(NBLK), dim3(256), 0, stream>>>(hp);
}